// Round 1
// baseline (538.230 us; speedup 1.0000x reference)
//
#include <hip/hip_runtime.h>
#include <stdint.h>
#include <math.h>

#define DEVI __device__ __forceinline__
typedef unsigned short ushort_t;
typedef __attribute__((ext_vector_type(8))) __bf16 bf16x8;
typedef __attribute__((ext_vector_type(4))) float f32x4;

// ---------- scalar bf16 helpers (RNE, matches HW/harness encoding) ----------
DEVI float bf2f(ushort_t b){ union{uint32_t u; float f;} c; c.u = ((uint32_t)b) << 16; return c.f; }
DEVI ushort_t f2bf(float f){ union{float f; uint32_t u;} c; c.f = f; uint32_t u = c.u;
                             u += 0x7fffu + ((u >> 16) & 1u); return (ushort_t)(u >> 16); }

// fast tanh: 1 - 2/(exp2(2*log2e*x)+1). ~5 VALU ops, saturates correctly.
DEVI float fast_tanh(float x){
  float t = __builtin_amdgcn_exp2f(x * 2.8853900817779268f);
  return 1.0f - 2.0f * __builtin_amdgcn_rcpf(t + 1.0f);
}

// ---------- async global->LDS (16B per lane, dest = wave-uniform base + lane*16) ----------
DEVI void async16(const ushort_t* g, ushort_t* l){
  __builtin_amdgcn_global_load_lds((const __attribute__((address_space(1))) void*)g,
                                   (__attribute__((address_space(3))) void*)l, 16, 0, 0);
}

// ---------- problem constants ----------
#define BB 32768
#define INDIM 256
#define LATENT 128
#define HID 1024
#define KCODES 1024

// =====================================================================
// dtype sniffer: flag = 1 -> buffers are bf16 ; flag = 0 -> fp32
// =====================================================================
__global__ void k_sniff(const ushort_t* __restrict__ act, int* flag){
  if (threadIdx.x == 0){
    int bad = 0;
    for (int i = 0; i < 256; i++){
      float v = bf2f(act[i]);
      float a = fabsf(v);
      if (!(a <= 16.0f) || (a > 0.0f && a < 9.5e-7f)) bad++;
    }
    flag[0] = (bad >= 8) ? 0 : 1;
  }
}

// convert (no transpose) to bf16 bits, 8 elements / thread (16B stores)
__global__ void k_cvt(const void* __restrict__ src, ushort_t* __restrict__ dst, int n8,
                      const int* __restrict__ flagp){
  int f = *flagp;
  int i = blockIdx.x * blockDim.x + threadIdx.x;
  if (i >= n8) return;
  if (f){
    ((uint4*)dst)[i] = ((const uint4*)src)[i];
  } else {
    const float* s = (const float*)src + (size_t)i * 8;
    ushort_t o[8];
    #pragma unroll
    for (int j = 0; j < 8; j++) o[j] = f2bf(s[j]);
    ((uint4*)dst)[i] = *(const uint4*)o;
  }
}

// all 6 weight transposes in ONE launch (was 6). src[R][C] -> dst[C][R] bf16.
// grid 2816 x 256: seg tile counts 256,1024,128,128,1024,256.
__global__ void k_tcvt6(const void* s0, ushort_t* d0, const void* s1, ushort_t* d1,
                        const void* s2, ushort_t* d2, const void* s3, ushort_t* d3,
                        const void* s4, ushort_t* d4, const void* s5, ushort_t* d5,
                        const int* __restrict__ flagp){
  __shared__ ushort_t tile[32][33];
  int f = *flagp;
  int t = blockIdx.x;
  const void* src; ushort_t* dst; int R, C, lcx;
  if (t < 256)      { src=s0; dst=d0; R=256;  C=1024; lcx=5; }
  else if (t < 1280){ src=s1; dst=d1; R=1024; C=1024; lcx=5; t-=256;  }
  else if (t < 1408){ src=s2; dst=d2; R=1024; C=128;  lcx=2; t-=1280; }
  else if (t < 1536){ src=s3; dst=d3; R=128;  C=1024; lcx=5; t-=1408; }
  else if (t < 2560){ src=s4; dst=d4; R=1024; C=1024; lcx=5; t-=1536; }
  else              { src=s5; dst=d5; R=1024; C=256;  lcx=3; t-=2560; }
  int bx = t & ((C >> 5) - 1), by = t >> lcx;
  int tx = threadIdx.x & 31, ty = threadIdx.x >> 5;
  int c = bx * 32 + tx;
  #pragma unroll
  for (int ii = 0; ii < 4; ii++){
    int r = by * 32 + ty + ii * 8;
    long idx = (long)r * C + c;
    tile[ty + ii * 8][tx] = f ? ((const ushort_t*)src)[idx] : f2bf(((const float*)src)[idx]);
  }
  __syncthreads();
  #pragma unroll
  for (int ii = 0; ii < 4; ii++){
    int cc = bx * 32 + ty + ii * 8;
    dst[(long)cc * R + by * 32 + tx] = tile[tx][ty + ii * 8];
  }
}

// all 6 biases -> fp32, 1024-float slots. grid 24 x 256
__global__ void k_bias(const void* s0, const void* s1, const void* s2,
                       const void* s3, const void* s4, const void* s5,
                       float* __restrict__ d, const int* __restrict__ flagp){
  int f = *flagp;
  int i = blockIdx.x * blockDim.x + threadIdx.x;
  int seg = i >> 10, off = i & 1023;
  const void* sp; int n;
  switch (seg){
    case 0: sp = s0; n = 1024; break;
    case 1: sp = s1; n = 1024; break;
    case 2: sp = s2; n = 128;  break;
    case 3: sp = s3; n = 1024; break;
    case 4: sp = s4; n = 1024; break;
    default: sp = s5; n = 256; break;
  }
  if (off < n)
    d[seg * 1024 + off] = f ? bf2f(((const ushort_t*)sp)[off]) : ((const float*)sp)[off];
}

// ||e_c||^2 from bf16 codebook. grid 4 x 256
__global__ void k_enorm(const ushort_t* __restrict__ embb, float* __restrict__ enorm){
  int c = blockIdx.x * blockDim.x + threadIdx.x;
  if (c < KCODES){
    float s = 0.f;
    for (int d = 0; d < LATENT; d++){ float v = bf2f(embb[c * LATENT + d]); s += v * v; }
    enorm[c] = s;
  }
}

// =====================================================================
// WIDE MFMA GEMM (N==1024): C = tanh(A[M,K] @ Bt[N,K]^T + b)
// Used for the SHORT-K layers (K=256 / K=128) where the drain-per-tile
// structure is latency-tolerable via 2 blocks/CU TLP.
// =====================================================================
__global__ __launch_bounds__(256, 2)
void k_gemmw(const ushort_t* __restrict__ A, const ushort_t* __restrict__ Bt,
             const float* __restrict__ bias, int K,
             ushort_t* __restrict__ outb)
{
  const int N = 1024;
  __shared__ __align__(16) ushort_t As[128 * 64];   // 16 KB
  __shared__ __align__(16) ushort_t Bs[256 * 64];   // 32 KB
  const int tid = threadIdx.x;
  const int w = tid >> 6, lane = tid & 63;
  const int lane15 = lane & 15, quad = lane >> 4;
  const int wr = w >> 1, wc = w & 1;

  // ---- XCD-locality swizzle: 4 n-tiles (256 wide), 256 m-tiles ----
  const int f = blockIdx.x;
  const int j8 = f & 7, s = f >> 3;
  const int n_idx = s & 3;
  const int m_idx = ((s >> 2) << 3) | j8;
  const long m0 = (long)m_idx * 128;
  const int n0 = n_idx * 256;

  // staging lane decomposition: r = lane>>3 (8 rows/shot), c = lane&7
  const int lrow = lane >> 3;
  const int lk8  = (((lane & 7) ^ (lrow & 7)) * 8);   // XOR-swizzled k-chunk
  // fragment-read chunk swizzle source: row rho -> rho&7
  const int rx   = lane15 & 7;

  f32x4 acc[4][8];
  #pragma unroll
  for (int i = 0; i < 4; i++)
    #pragma unroll
    for (int j = 0; j < 8; j++) acc[i][j] = (f32x4){0.f, 0.f, 0.f, 0.f};

  const int nk = K >> 6;
  for (int kb = 0; kb < nk; kb++){
    const int k0 = kb << 6;
    __syncthreads();
    #pragma unroll
    for (int a = 0; a < 4; a++){
      int m = w * 32 + a * 8 + lrow;
      async16(A + ((m0 + m) * K + k0 + lk8), &As[(w * 32 + a * 8) * 64]);
    }
    #pragma unroll
    for (int b = 0; b < 8; b++){
      int n = w * 64 + b * 8 + lrow;
      async16(Bt + ((long)(n0 + n) * K + k0 + lk8), &Bs[(w * 64 + b * 8) * 64]);
    }
    __builtin_amdgcn_s_waitcnt(0);
    __syncthreads();

    #pragma unroll
    for (int h = 0; h < 2; h++){
      bf16x8 af[4], bf[8];
      #pragma unroll
      for (int i = 0; i < 4; i++){
        int rho = wr * 64 + i * 16 + lane15;
        af[i] = *(const bf16x8*)&As[rho * 64 + ((((h << 2) | quad) ^ rx) * 8)];
      }
      #pragma unroll
      for (int j = 0; j < 8; j++){
        int rho = wc * 128 + j * 16 + lane15;
        bf[j] = *(const bf16x8*)&Bs[rho * 64 + ((((h << 2) | quad) ^ rx) * 8)];
      }
      #pragma unroll
      for (int i = 0; i < 4; i++)
        #pragma unroll
        for (int j = 0; j < 8; j++)
          acc[i][j] = __builtin_amdgcn_mfma_f32_16x16x32_bf16(af[i], bf[j], acc[i][j], 0, 0, 0);
    }
  }

  #pragma unroll
  for (int i = 0; i < 4; i++){
    int row_l = wr * 64 + i * 16 + quad * 4;
    #pragma unroll
    for (int j = 0; j < 8; j++){
      int col = n0 + wc * 128 + j * 16 + lane15;
      float b = bias[col];
      #pragma unroll
      for (int r = 0; r < 4; r++){
        float v = fast_tanh(acc[i][j][r] + b);
        outb[(m0 + row_l + r) * N + col] = f2bf(v);
      }
    }
  }
}

// =====================================================================
// 8-PHASE 256x256 MFMA GEMM (N==1024, K%128==0): enc-L1 / dec-L1.
// Port of the learn_hip m201 template (T2+T3+T4+T5):
//   BK=64, 512 threads (8 waves = 2M x 4N), per-wave 128x64 output,
//   LDS 128 KiB double-buffered (A 2x32K, B 2x32K).
//   Pipeline: tile t+1's 8 global_load_lds issued at tile-t start,
//   s_waitcnt vmcnt(8) (NEVER 0 in main loop) + raw s_barrier — load
//   latency hides under the full K-tile of MFMA. 4 phases per K-tile:
//   {4/8 ds_read_b128; BAR; lgkmcnt(0); setprio(1); 16 MFMA; setprio(0);
//   BAR}, sched_barrier(0) pins at each boundary (rule #18 hazards).
//   XOR k-chunk swizzle identical to k_gemmw (measured 0 bank conflicts):
//   LDS slot (r,c) holds global chunk c^(r&7); readers XOR identically.
// =====================================================================
#define BAR8()  __builtin_amdgcn_s_barrier()
#define SCB8()  __builtin_amdgcn_sched_barrier(0)
#define VMC8(n) asm volatile("s_waitcnt vmcnt(" #n ")" ::: "memory")

__global__ __launch_bounds__(512, 2)
void k_gemm8(const ushort_t* __restrict__ A, const ushort_t* __restrict__ Bt,
             const float* __restrict__ bias, int K, ushort_t* __restrict__ outb)
{
  const int N = 1024;
  __shared__ __align__(16) ushort_t As[2][256 * 64];   // 64 KB
  __shared__ __align__(16) ushort_t Bs[2][256 * 64];   // 64 KB
  const int tid = threadIdx.x;
  const int w = tid >> 6, lane = tid & 63;
  const int lane15 = lane & 15, quad = lane >> 4;
  const int rx = lane15 & 7;
  const int wr = w >> 2, wc = w & 3;   // 2 x 4 wave grid

  // XCD swizzle: 128 m-tiles x 4 n-tiles = 512 blocks (divisible by 8)
  const int f = blockIdx.x;
  const int j8 = f & 7, s = f >> 3;
  const int n_idx = s & 3;
  const int m_idx = ((s >> 2) << 3) | j8;
  const long m0 = (long)m_idx * 256;
  const int n0 = n_idx * 256;

  // staging lane decomposition: 8 rows x 8 k-chunks per wave per slab
  const int lrow = lane >> 3;                     // 0..7
  const int lk8  = (((lane & 7) ^ lrow) << 3);    // XOR-swizzled source chunk

  // per-thread global row pointers, 4 slabs of 64 rows each for A and B
  const ushort_t* aP[4]; const ushort_t* bP[4];
  #pragma unroll
  for (int s4 = 0; s4 < 4; s4++){
    aP[s4] = A  + (m0 + s4 * 64 + w * 8 + lrow) * (long)K + lk8;
    bP[s4] = Bt + ((long)(n0 + s4 * 64 + w * 8 + lrow)) * K + lk8;
  }

  f32x4 acc[8][4];
  #pragma unroll
  for (int i = 0; i < 8; i++)
    #pragma unroll
    for (int j = 0; j < 4; j++) acc[i][j] = (f32x4){0.f, 0.f, 0.f, 0.f};

  const int nk = K >> 6;   // K % 128 == 0 -> nk even

#define STAGE8(BUF, K0)                                                       \
  { _Pragma("unroll")                                                         \
    for (int s4 = 0; s4 < 4; s4++)                                            \
      async16(aP[s4] + (K0), &As[BUF][(s4 * 64 + w * 8) * 64]);               \
    _Pragma("unroll")                                                         \
    for (int s4 = 0; s4 < 4; s4++)                                            \
      async16(bP[s4] + (K0), &Bs[BUF][(s4 * 64 + w * 8) * 64]); }

#define TILE8(BUF, KB)                                                        \
  { if ((KB) + 1 < nk){ STAGE8((BUF) ^ 1, (((KB) + 1) << 6)); VMC8(8); }      \
    else              { VMC8(0); }                                            \
    BAR8(); SCB8();                                                           \
    _Pragma("unroll")                                                         \
    for (int kk = 0; kk < 2; kk++){                                           \
      bf16x8 bf[4];                                                           \
      _Pragma("unroll")                                                       \
      for (int mh = 0; mh < 2; mh++){                                         \
        bf16x8 af[4];                                                         \
        _Pragma("unroll")                                                     \
        for (int i = 0; i < 4; i++){                                          \
          int rho = wr * 128 + (mh * 4 + i) * 16 + lane15;                    \
          af[i] = *(const bf16x8*)&As[BUF][rho * 64 + ((((kk << 2) | quad) ^ rx) * 8)]; \
        }                                                                     \
        if (mh == 0){                                                         \
          _Pragma("unroll")                                                   \
          for (int j = 0; j < 4; j++){                                        \
            int rho = wc * 64 + j * 16 + lane15;                              \
            bf[j] = *(const bf16x8*)&Bs[BUF][rho * 64 + ((((kk << 2) | quad) ^ rx) * 8)]; \
          }                                                                   \
        }                                                                     \
        BAR8();                                                               \
        asm volatile("s_waitcnt lgkmcnt(0)" ::: "memory");                    \
        SCB8();                                                               \
        __builtin_amdgcn_s_setprio(1);                                        \
        _Pragma("unroll")                                                     \
        for (int i = 0; i < 4; i++)                                           \
          _Pragma("unroll")                                                   \
          for (int j = 0; j < 4; j++)                                         \
            acc[mh * 4 + i][j] = __builtin_amdgcn_mfma_f32_16x16x32_bf16(af[i], bf[j], acc[mh * 4 + i][j], 0, 0, 0); \
        __builtin_amdgcn_s_setprio(0);                                        \
        SCB8();                                                               \
        BAR8();                                                               \
      }                                                                       \
    } }

  STAGE8(0, 0);
  for (int kb = 0; kb < nk; kb += 2){
    TILE8(0, kb);
    TILE8(1, kb + 1);
  }
#undef STAGE8
#undef TILE8

  // epilogue: bias + tanh + bf16 store
  #pragma unroll
  for (int mf = 0; mf < 8; mf++){
    int row_l = wr * 128 + mf * 16 + quad * 4;
    #pragma unroll
    for (int nf = 0; nf < 4; nf++){
      int col = n0 + wc * 64 + nf * 16 + lane15;
      float b = bias[col];
      #pragma unroll
      for (int r = 0; r < 4; r++){
        float v = fast_tanh(acc[mf][nf][r] + b);
        outb[(m0 + row_l + r) * N + col] = f2bf(v);
      }
    }
  }
}

// =====================================================================
// generic 128x128 MFMA GEMM (z / VQ / dec-L2 shapes). BK=32.
// MODE 1: z: fp32 buf + bf16 buf + d_out (flag dtype)      [N=128]
// MODE 2: recon: d_out only (flag dtype)                   [N=256]
// MODE 3: VQ scores: acc - 0.5*enorm[col], per-row argmax  [N=1024]
// =====================================================================
template<int MODE>
__global__ __launch_bounds__(256)
void k_gemm(const ushort_t* __restrict__ A, const ushort_t* __restrict__ Bt,
            const float* __restrict__ bias, int N, int K,
            ushort_t* __restrict__ outb, float* __restrict__ outf,
            void* __restrict__ dout, long dout_off,
            const float* __restrict__ enorm,
            float* __restrict__ cand_v, int* __restrict__ cand_i,
            const int* __restrict__ flagp)
{
  __shared__ __align__(16) ushort_t As[128 * 32];
  __shared__ __align__(16) ushort_t Bs[128 * 32];
  const int tid = threadIdx.x;
  const int w = tid >> 6, lane = tid & 63;
  const int lane15 = lane & 15, quad = lane >> 4;
  const int wr = w >> 1, wc = w & 1;

  const int nx = N >> 7;
  const int lnx = __builtin_ctz(nx);
  const int f = blockIdx.x;
  const int j8 = f & 7, s = f >> 3;
  const int n_idx = s & (nx - 1);
  const int m_idx = ((s >> lnx) << 3) | j8;
  const long m0 = (long)m_idx * 128;
  const int n0 = n_idx * 128;

  const int lrow = lane >> 2;
  const int lk8  = (((lane & 3) ^ ((lane >> 3) & 3)) * 8);
  const int sw   = (lane15 >> 1) & 3;

  f32x4 acc[4][4];
  #pragma unroll
  for (int i = 0; i < 4; i++)
    #pragma unroll
    for (int j = 0; j < 4; j++) acc[i][j] = (f32x4){0.f, 0.f, 0.f, 0.f};

  const int nk = K >> 5;
  for (int kb = 0; kb < nk; kb++){
    const int k0 = kb << 5;
    __syncthreads();
    #pragma unroll
    for (int ss = 0; ss < 2; ss++){
      int m = w * 32 + ss * 16 + lrow;
      async16(A + ((m0 + m) * K + k0 + lk8), &As[(w * 32 + ss * 16) * 32]);
    }
    #pragma unroll
    for (int ss = 0; ss < 2; ss++){
      int n = w * 32 + ss * 16 + lrow;
      async16(Bt + ((long)(n0 + n) * K + k0 + lk8), &Bs[(w * 32 + ss * 16) * 32]);
    }
    __builtin_amdgcn_s_waitcnt(0);
    __syncthreads();

    bf16x8 af[4], bf[4];
    #pragma unroll
    for (int i = 0; i < 4; i++)
      af[i] = *(const bf16x8*)&As[(wr * 64 + i * 16 + lane15) * 32 + ((quad ^ sw) * 8)];
    #pragma unroll
    for (int j = 0; j < 4; j++)
      bf[j] = *(const bf16x8*)&Bs[(wc * 64 + j * 16 + lane15) * 32 + ((quad ^ sw) * 8)];
    #pragma unroll
    for (int i = 0; i < 4; i++)
      #pragma unroll
      for (int j = 0; j < 4; j++)
        acc[i][j] = __builtin_amdgcn_mfma_f32_16x16x32_bf16(af[i], bf[j], acc[i][j], 0, 0, 0);
  }

  if (MODE == 1){
    int fl = *flagp;
    #pragma unroll
    for (int i = 0; i < 4; i++){
      int row_l = wr * 64 + i * 16 + quad * 4;
      #pragma unroll
      for (int j = 0; j < 4; j++){
        int col = wc * 64 + j * 16 + lane15;   // N==128, n0==0
        float b = bias[col];
        #pragma unroll
        for (int r = 0; r < 4; r++){
          float v = acc[i][j][r] + b;
          long idx = (m0 + row_l + r) * 128 + col;
          outf[idx] = v;
          ushort_t bb = f2bf(v);
          outb[idx] = bb;
          if (fl) ((ushort_t*)dout)[dout_off + idx] = bb;
          else    ((float*)dout)[dout_off + idx] = v;
        }
      }
    }
  } else if (MODE == 2){
    int fl = *flagp;
    #pragma unroll
    for (int i = 0; i < 4; i++){
      int row_l = wr * 64 + i * 16 + quad * 4;
      #pragma unroll
      for (int j = 0; j < 4; j++){
        int col = n0 + wc * 64 + j * 16 + lane15;
        float b = bias[col];
        #pragma unroll
        for (int r = 0; r < 4; r++){
          float v = acc[i][j][r] + b;
          long idx = (m0 + row_l + r) * N + col;
          if (fl) ((ushort_t*)dout)[dout_off + idx] = f2bf(v);
          else    ((float*)dout)[dout_off + idx] = v;
        }
      }
    }
  } else { // MODE 3
    float bestv[16]; int bestc[16];
    #pragma unroll
    for (int i = 0; i < 4; i++){
      #pragma unroll
      for (int r = 0; r < 4; r++){
        float best = -1e30f; int bcol = 0;
        #pragma unroll
        for (int j = 0; j < 4; j++){
          int col = n0 + wc * 64 + j * 16 + lane15;
          float v = acc[i][j][r] - 0.5f * enorm[col];
          if (v > best){ best = v; bcol = col; }
        }
        #pragma unroll
        for (int off = 1; off < 16; off <<= 1){
          float ov = __shfl_xor(best, off, 64);
          int   oc = __shfl_xor(bcol, off, 64);
          if (ov > best || (ov == best && oc < bcol)){ best = ov; bcol = oc; }
        }
        bestv[i * 4 + r] = best; bestc[i * 4 + r] = bcol;
      }
    }
    __syncthreads();
    float* lv = (float*)As;
    int*   li = (int*)Bs;
    #pragma unroll
    for (int i = 0; i < 4; i++)
      #pragma unroll
      for (int r = 0; r < 4; r++){
        int row_l = wr * 64 + i * 16 + quad * 4 + r;
        if (lane15 == 0){ lv[row_l * 2 + wc] = bestv[i * 4 + r]; li[row_l * 2 + wc] = bestc[i * 4 + r]; }
      }
    __syncthreads();
    if (tid < 128){
      float v0 = lv[tid * 2], v1 = lv[tid * 2 + 1];
      int   c0 = li[tid * 2], c1 = li[tid * 2 + 1];
      float bv; int bc;
      if (v1 > v0 || (v1 == v0 && c1 < c0)){ bv = v1; bc = c1; } else { bv = v0; bc = c0; }
      long row = m0 + tid;
      cand_v[row * 8 + n_idx] = bv;
      cand_i[row * 8 + n_idx] = bc;
    }
  }
}

// =====================================================================
// VQ finalize. grid 16384, block 256 (2 rows / block)
// =====================================================================
__global__ __launch_bounds__(256)
void k_vqfin(const float* __restrict__ cand_v, const int* __restrict__ cand_i,
             const float* __restrict__ zf, const ushort_t* __restrict__ embb,
             ushort_t* __restrict__ qb, void* __restrict__ dout, long zq_off,
             float* __restrict__ loss_part, const int* __restrict__ flagp)
{
  int f = *flagp;
  long row = (long)blockIdx.x * 2 + (threadIdx.x >> 7);
  int d = threadIdx.x & 127;
  float best = -1e30f; int bi = 0;
  #pragma unroll
  for (int nb = 0; nb < 8; nb++){
    float v = cand_v[row * 8 + nb]; int c = cand_i[row * 8 + nb];
    if (v > best || (v == best && c < bi)){ best = v; bi = c; }
  }
  ushort_t qbits = embb[(long)bi * LATENT + d];
  float q = bf2f(qbits);
  long idx = row * LATENT + d;
  qb[idx] = qbits;
  if (f) ((ushort_t*)dout)[zq_off + idx] = qbits;
  else   ((float*)dout)[zq_off + idx] = q;
  float diff = zf[idx] - q;
  float p = diff * diff;
  #pragma unroll
  for (int off = 32; off; off >>= 1) p += __shfl_down(p, off, 64);
  __shared__ float red[4];
  if ((threadIdx.x & 63) == 0) red[threadIdx.x >> 6] = p;
  __syncthreads();
  if (threadIdx.x == 0) loss_part[blockIdx.x] = red[0] + red[1] + red[2] + red[3];
}

__global__ __launch_bounds__(256)
void k_lossfin(const float* __restrict__ loss_part, void* __restrict__ dout,
               long off, const int* __restrict__ flagp){
  __shared__ float red[4];
  float s = 0.f;
  for (int i = threadIdx.x; i < BB / 2; i += 256) s += loss_part[i];
  #pragma unroll
  for (int o = 32; o; o >>= 1) s += __shfl_down(s, o, 64);
  if ((threadIdx.x & 63) == 0) red[threadIdx.x >> 6] = s;
  __syncthreads();
  if (threadIdx.x == 0){
    float v = 1.25f * (red[0] + red[1] + red[2] + red[3]) / (float)((long)BB * LATENT);
    if (*flagp) ((ushort_t*)dout)[off] = f2bf(v);
    else        ((float*)dout)[off] = v;
  }
}

// =====================================================================
extern "C" void kernel_launch(void* const* d_in, const int* in_sizes, int n_in,
                              void* d_out, int out_size, void* d_ws, size_t ws_size,
                              hipStream_t stream)
{
  (void)in_sizes; (void)n_in; (void)out_size; (void)ws_size;
  const void* action = d_in[1];
  const void* eW0 = d_in[2];  const void* eb0 = d_in[3];
  const void* eW1 = d_in[4];  const void* eb1 = d_in[5];
  const void* eW2 = d_in[6];  const void* eb2 = d_in[7];
  const void* emb = d_in[8];
  const void* dW0 = d_in[9];  const void* db0 = d_in[10];
  const void* dW1 = d_in[11]; const void* db1 = d_in[12];
  const void* dW2 = d_in[13]; const void* db2 = d_in[14];

  char* ws = (char*)d_ws;
  size_t off = 0;
  auto alloc = [&](size_t bytes)->char*{
    char* p = ws + off; off += bytes; off = (off + 255) & ~((size_t)255); return p;
  };
  int*      flag     = (int*)  alloc(4);
  float*    biasf    = (float*)alloc(6 * 1024 * 4);
  float*    enorm    = (float*)alloc(KCODES * 4);
  ushort_t* eW0t = (ushort_t*)alloc((size_t)HID * INDIM * 2);
  ushort_t* eW1t = (ushort_t*)alloc((size_t)HID * HID * 2);
  ushort_t* eW2t = (ushort_t*)alloc((size_t)LATENT * HID * 2);
  ushort_t* embb = (ushort_t*)alloc((size_t)KCODES * LATENT * 2);
  ushort_t* dW0t = (ushort_t*)alloc((size_t)HID * LATENT * 2);
  ushort_t* dW1t = (ushort_t*)alloc((size_t)HID * HID * 2);
  ushort_t* dW2t = (ushort_t*)alloc((size_t)INDIM * HID * 2);
  ushort_t* act0 = (ushort_t*)alloc((size_t)BB * INDIM * 2);
  ushort_t* hA   = (ushort_t*)alloc((size_t)BB * HID * 2);
  ushort_t* hB   = (ushort_t*)alloc((size_t)BB * HID * 2);
  float*    zf32 = (float*)   alloc((size_t)BB * LATENT * 4);
  ushort_t* zb16 = (ushort_t*)alloc((size_t)BB * LATENT * 2);
  ushort_t* qb16 = (ushort_t*)alloc((size_t)BB * LATENT * 2);
  float*    cand_v = (float*) alloc((size_t)BB * 8 * 4);
  int*      cand_i = (int*)   alloc((size_t)BB * 8 * 4);
  float*    loss_part = (float*)alloc((size_t)(BB / 2) * 4);

  const long z_off  = (long)BB * INDIM;
  const long zq_off = z_off + (long)BB * LATENT;
  const long l_off  = zq_off + (long)BB * LATENT;

  // ---- prep ----
  k_sniff<<<1, 64, 0, stream>>>((const ushort_t*)action, flag);
  k_cvt<<<(BB * INDIM / 8 + 255) / 256, 256, 0, stream>>>(action, act0, BB * INDIM / 8, flag);
  k_tcvt6<<<2816, 256, 0, stream>>>(eW0, eW0t, eW1, eW1t, eW2, eW2t,
                                    dW0, dW0t, dW1, dW1t, dW2, dW2t, flag);
  k_cvt<<<(KCODES * LATENT / 8 + 255) / 256, 256, 0, stream>>>(emb, embb, KCODES * LATENT / 8, flag);
  k_bias<<<24, 256, 0, stream>>>(eb0, eb1, eb2, db0, db1, db2, biasf, flag);
  k_enorm<<<4, 256, 0, stream>>>(embb, enorm);

  // ---- encoder ----
  k_gemmw<<<1024, 256, 0, stream>>>(act0, eW0t, biasf + 0, INDIM, hA);        // K=256: short-K kernel
  k_gemm8<<<512, 512, 0, stream>>>(hA, eW1t, biasf + 1024, HID, hB);          // K=1024: 8-phase kernel
  k_gemm<1><<<1 * 256, 256, 0, stream>>>(hB, eW2t, biasf + 2048, LATENT, HID,
      zb16, zf32, d_out, z_off, nullptr, nullptr, nullptr, flag);

  // ---- VQ ----
  k_gemm<3><<<8 * 256, 256, 0, stream>>>(zb16, embb, nullptr, KCODES, LATENT,
      nullptr, nullptr, nullptr, 0, enorm, cand_v, cand_i, flag);
  k_vqfin<<<BB / 2, 256, 0, stream>>>(cand_v, cand_i, zf32, embb, qb16, d_out, zq_off,
      loss_part, flag);

  // ---- decoder ----
  k_gemmw<<<1024, 256, 0, stream>>>(qb16, dW0t, biasf + 3072, LATENT, hA);    // K=128: short-K kernel
  k_gemm8<<<512, 512, 0, stream>>>(hA, dW1t, biasf + 4096, HID, hB);          // K=1024: 8-phase kernel
  k_gemm<2><<<2 * 256, 256, 0, stream>>>(hB, dW2t, biasf + 5120, INDIM, HID,
      nullptr, nullptr, d_out, 0, nullptr, nullptr, nullptr, flag);

  k_lossfin<<<1, 256, 0, stream>>>(loss_part, d_out, l_off, flag);
}

// Round 2
// 462.770 us; speedup vs baseline: 1.1631x; 1.1631x over previous
//
#include <hip/hip_runtime.h>
#include <stdint.h>
#include <math.h>

#define DEVI __device__ __forceinline__
typedef unsigned short ushort_t;
typedef __attribute__((ext_vector_type(8))) __bf16 bf16x8;
typedef __attribute__((ext_vector_type(4))) float f32x4;

// ---------- scalar bf16 helpers (RNE, matches HW/harness encoding) ----------
DEVI float bf2f(ushort_t b){ union{uint32_t u; float f;} c; c.u = ((uint32_t)b) << 16; return c.f; }
DEVI ushort_t f2bf(float f){ union{float f; uint32_t u;} c; c.f = f; uint32_t u = c.u;
                             u += 0x7fffu + ((u >> 16) & 1u); return (ushort_t)(u >> 16); }

// fast tanh: 1 - 2/(exp2(2*log2e*x)+1). ~5 VALU ops, saturates correctly.
DEVI float fast_tanh(float x){
  float t = __builtin_amdgcn_exp2f(x * 2.8853900817779268f);
  return 1.0f - 2.0f * __builtin_amdgcn_rcpf(t + 1.0f);
}

// ---------- async global->LDS (16B per lane, dest = wave-uniform base + lane*16) ----------
DEVI void async16(const ushort_t* g, ushort_t* l){
  __builtin_amdgcn_global_load_lds((const __attribute__((address_space(1))) void*)g,
                                   (__attribute__((address_space(3))) void*)l, 16, 0, 0);
}

// ---------- problem constants ----------
#define BB 32768
#define INDIM 256
#define LATENT 128
#define HID 1024
#define KCODES 1024

// =====================================================================
// dtype sniffer: flag = 1 -> buffers are bf16 ; flag = 0 -> fp32
// =====================================================================
__global__ void k_sniff(const ushort_t* __restrict__ act, int* flag){
  if (threadIdx.x == 0){
    int bad = 0;
    for (int i = 0; i < 256; i++){
      float v = bf2f(act[i]);
      float a = fabsf(v);
      if (!(a <= 16.0f) || (a > 0.0f && a < 9.5e-7f)) bad++;
    }
    flag[0] = (bad >= 8) ? 0 : 1;
  }
}

// merged prep: action->bf16, emb->bf16, 6 biases->fp32, ONE launch.
// segment sizes: A8=BB*INDIM/8, E8=KCODES*LATENT/8, 6144 bias slots.
__global__ void k_prep(const void* __restrict__ act_src, ushort_t* __restrict__ act_dst,
                       const void* __restrict__ emb_src, ushort_t* __restrict__ emb_dst,
                       const void* b0, const void* b1, const void* b2,
                       const void* b3, const void* b4, const void* b5,
                       float* __restrict__ biasf, const int* __restrict__ flagp){
  const int f = *flagp;
  const int A8 = BB * INDIM / 8;
  const int E8 = KCODES * LATENT / 8;
  int i = blockIdx.x * blockDim.x + threadIdx.x;
  if (i < A8 + E8){
    const void* src; ushort_t* dst; int k;
    if (i < A8){ src = act_src; dst = act_dst; k = i; }
    else       { src = emb_src; dst = emb_dst; k = i - A8; }
    if (f){
      ((uint4*)dst)[k] = ((const uint4*)src)[k];
    } else {
      const float* s = (const float*)src + (size_t)k * 8;
      ushort_t o[8];
      #pragma unroll
      for (int j = 0; j < 8; j++) o[j] = f2bf(s[j]);
      ((uint4*)dst)[k] = *(const uint4*)o;
    }
  } else {
    int k = i - A8 - E8;
    if (k < 6144){
      int seg = k >> 10, off = k & 1023;
      const void* sp; int n;
      switch (seg){
        case 0: sp = b0; n = 1024; break;
        case 1: sp = b1; n = 1024; break;
        case 2: sp = b2; n = 128;  break;
        case 3: sp = b3; n = 1024; break;
        case 4: sp = b4; n = 1024; break;
        default: sp = b5; n = 256; break;
      }
      if (off < n)
        biasf[seg * 1024 + off] = f ? bf2f(((const ushort_t*)sp)[off]) : ((const float*)sp)[off];
    }
  }
}

// all 6 weight transposes in ONE launch. src[R][C] -> dst[C][R] bf16.
// grid 2816 x 256: seg tile counts 256,1024,128,128,1024,256.
__global__ void k_tcvt6(const void* s0, ushort_t* d0, const void* s1, ushort_t* d1,
                        const void* s2, ushort_t* d2, const void* s3, ushort_t* d3,
                        const void* s4, ushort_t* d4, const void* s5, ushort_t* d5,
                        const int* __restrict__ flagp){
  __shared__ ushort_t tile[32][33];
  int f = *flagp;
  int t = blockIdx.x;
  const void* src; ushort_t* dst; int R, C, lcx;
  if (t < 256)      { src=s0; dst=d0; R=256;  C=1024; lcx=5; }
  else if (t < 1280){ src=s1; dst=d1; R=1024; C=1024; lcx=5; t-=256;  }
  else if (t < 1408){ src=s2; dst=d2; R=1024; C=128;  lcx=2; t-=1280; }
  else if (t < 1536){ src=s3; dst=d3; R=128;  C=1024; lcx=5; t-=1408; }
  else if (t < 2560){ src=s4; dst=d4; R=1024; C=1024; lcx=5; t-=1536; }
  else              { src=s5; dst=d5; R=1024; C=256;  lcx=3; t-=2560; }
  int bx = t & ((C >> 5) - 1), by = t >> lcx;
  int tx = threadIdx.x & 31, ty = threadIdx.x >> 5;
  int c = bx * 32 + tx;
  #pragma unroll
  for (int ii = 0; ii < 4; ii++){
    int r = by * 32 + ty + ii * 8;
    long idx = (long)r * C + c;
    tile[ty + ii * 8][tx] = f ? ((const ushort_t*)src)[idx] : f2bf(((const float*)src)[idx]);
  }
  __syncthreads();
  #pragma unroll
  for (int ii = 0; ii < 4; ii++){
    int cc = bx * 32 + ty + ii * 8;
    dst[(long)cc * R + by * 32 + tx] = tile[tx][ty + ii * 8];
  }
}

// ||e_c||^2 from bf16 codebook. grid 4 x 256
__global__ void k_enorm(const ushort_t* __restrict__ embb, float* __restrict__ enorm){
  int c = blockIdx.x * blockDim.x + threadIdx.x;
  if (c < KCODES){
    float s = 0.f;
    for (int d = 0; d < LATENT; d++){ float v = bf2f(embb[c * LATENT + d]); s += v * v; }
    enorm[c] = s;
  }
}

// =====================================================================
// WIDE MFMA GEMM (N==1024): C = tanh(A[M,K] @ Bt[N,K]^T + b)
// 128x256 block tile, BK=64. Proven 73us / 40% MfmaUtil on K=1024.
// Staging rows are 64-k (8 chunks of 8 elem); slot (r,c) holds global
// chunk c^(r&7); reader XORs identically -> 2-way banks (free).
// =====================================================================
__global__ __launch_bounds__(256, 2)
void k_gemmw(const ushort_t* __restrict__ A, const ushort_t* __restrict__ Bt,
             const float* __restrict__ bias, int K,
             ushort_t* __restrict__ outb)
{
  const int N = 1024;
  __shared__ __align__(16) ushort_t As[128 * 64];   // 16 KB
  __shared__ __align__(16) ushort_t Bs[256 * 64];   // 32 KB
  const int tid = threadIdx.x;
  const int w = tid >> 6, lane = tid & 63;
  const int lane15 = lane & 15, quad = lane >> 4;
  const int wr = w >> 1, wc = w & 1;

  // ---- XCD-locality swizzle: 4 n-tiles (256 wide), 256 m-tiles ----
  const int f = blockIdx.x;
  const int j8 = f & 7, s = f >> 3;
  const int n_idx = s & 3;
  const int m_idx = ((s >> 2) << 3) | j8;
  const long m0 = (long)m_idx * 128;
  const int n0 = n_idx * 256;

  // staging lane decomposition: r = lane>>3 (8 rows/shot), c = lane&7
  const int lrow = lane >> 3;
  const int lk8  = (((lane & 7) ^ (lrow & 7)) * 8);   // XOR-swizzled k-chunk
  const int rx   = lane15 & 7;

  f32x4 acc[4][8];
  #pragma unroll
  for (int i = 0; i < 4; i++)
    #pragma unroll
    for (int j = 0; j < 8; j++) acc[i][j] = (f32x4){0.f, 0.f, 0.f, 0.f};

  const int nk = K >> 6;
  for (int kb = 0; kb < nk; kb++){
    const int k0 = kb << 6;
    __syncthreads();
    #pragma unroll
    for (int a = 0; a < 4; a++){
      int m = w * 32 + a * 8 + lrow;
      async16(A + ((m0 + m) * K + k0 + lk8), &As[(w * 32 + a * 8) * 64]);
    }
    #pragma unroll
    for (int b = 0; b < 8; b++){
      int n = w * 64 + b * 8 + lrow;
      async16(Bt + ((long)(n0 + n) * K + k0 + lk8), &Bs[(w * 64 + b * 8) * 64]);
    }
    __builtin_amdgcn_s_waitcnt(0);
    __syncthreads();

    #pragma unroll
    for (int h = 0; h < 2; h++){
      bf16x8 af[4], bf[8];
      #pragma unroll
      for (int i = 0; i < 4; i++){
        int rho = wr * 64 + i * 16 + lane15;
        af[i] = *(const bf16x8*)&As[rho * 64 + ((((h << 2) | quad) ^ rx) * 8)];
      }
      #pragma unroll
      for (int j = 0; j < 8; j++){
        int rho = wc * 128 + j * 16 + lane15;
        bf[j] = *(const bf16x8*)&Bs[rho * 64 + ((((h << 2) | quad) ^ rx) * 8)];
      }
      #pragma unroll
      for (int i = 0; i < 4; i++)
        #pragma unroll
        for (int j = 0; j < 8; j++)
          acc[i][j] = __builtin_amdgcn_mfma_f32_16x16x32_bf16(af[i], bf[j], acc[i][j], 0, 0, 0);
    }
  }

  #pragma unroll
  for (int i = 0; i < 4; i++){
    int row_l = wr * 64 + i * 16 + quad * 4;
    #pragma unroll
    for (int j = 0; j < 8; j++){
      int col = n0 + wc * 128 + j * 16 + lane15;
      float b = bias[col];
      #pragma unroll
      for (int r = 0; r < 4; r++){
        float v = fast_tanh(acc[i][j][r] + b);
        outb[(m0 + row_l + r) * N + col] = f2bf(v);
      }
    }
  }
}

// =====================================================================
// SLIM MFMA GEMM: 64xBN block tile, BK=64, 4 waves, wave = 32 x BN/2.
// Same staging/fragment structure as k_gemmw (proven), smaller LDS
// (24/40 KB) -> 3-6 blocks/CU for wave-level TLP over the drains.
// MODE 0: tanh -> bf16 buffer outb (N-stride cols)          [L0 layers]
// MODE 1: z: fp32 buf + bf16 buf + d_out (flag dtype)       [N=BN=128]
// MODE 2: recon: d_out only (flag dtype)                    [N=BN=256]
// =====================================================================
template<int MODE, int BN>
__global__ __launch_bounds__(256)
void k_gemm64(const ushort_t* __restrict__ A, const ushort_t* __restrict__ Bt,
              const float* __restrict__ bias, int N, int K,
              ushort_t* __restrict__ outb, float* __restrict__ outf,
              void* __restrict__ dout, long dout_off,
              const int* __restrict__ flagp)
{
  constexpr int NJ = BN / 32;                 // j-frags per wave: 8 (BN=256) / 4 (BN=128)
  __shared__ __align__(16) ushort_t As[64 * 64];    // 8 KB
  __shared__ __align__(16) ushort_t Bs[BN * 64];    // 32/16 KB
  const int tid = threadIdx.x;
  const int w = tid >> 6, lane = tid & 63;
  const int lane15 = lane & 15, quad = lane >> 4;
  const int wr = w >> 1, wc = w & 1;

  const int nx = N / BN;                      // 1 or 4
  const int lnx = __builtin_ctz(nx);
  const int f = blockIdx.x;
  const int j8 = f & 7, s = f >> 3;
  const int n_idx = s & (nx - 1);
  const int m_idx = ((s >> lnx) << 3) | j8;
  const long m0 = (long)m_idx * 64;
  const int n0 = n_idx * BN;

  const int lrow = lane >> 3;
  const int lk8  = (((lane & 7) ^ lrow) << 3);
  const int rx   = lane15 & 7;

  f32x4 acc[2][NJ];
  #pragma unroll
  for (int i = 0; i < 2; i++)
    #pragma unroll
    for (int j = 0; j < NJ; j++) acc[i][j] = (f32x4){0.f, 0.f, 0.f, 0.f};

  const int nk = K >> 6;
  for (int kb = 0; kb < nk; kb++){
    const int k0 = kb << 6;
    __syncthreads();
    #pragma unroll
    for (int a = 0; a < 2; a++){
      int m = w * 16 + a * 8 + lrow;
      async16(A + ((m0 + m) * K + k0 + lk8), &As[(w * 16 + a * 8) * 64]);
    }
    #pragma unroll
    for (int b = 0; b < NJ; b++){
      int n = w * (BN / 4) + b * 8 + lrow;
      async16(Bt + ((long)(n0 + n) * K + k0 + lk8), &Bs[(w * (BN / 4) + b * 8) * 64]);
    }
    __builtin_amdgcn_s_waitcnt(0);
    __syncthreads();

    #pragma unroll
    for (int h = 0; h < 2; h++){
      bf16x8 af[2], bf[NJ];
      #pragma unroll
      for (int i = 0; i < 2; i++){
        int rho = wr * 32 + i * 16 + lane15;
        af[i] = *(const bf16x8*)&As[rho * 64 + ((((h << 2) | quad) ^ rx) * 8)];
      }
      #pragma unroll
      for (int j = 0; j < NJ; j++){
        int rho = wc * (BN / 2) + j * 16 + lane15;
        bf[j] = *(const bf16x8*)&Bs[rho * 64 + ((((h << 2) | quad) ^ rx) * 8)];
      }
      #pragma unroll
      for (int i = 0; i < 2; i++)
        #pragma unroll
        for (int j = 0; j < NJ; j++)
          acc[i][j] = __builtin_amdgcn_mfma_f32_16x16x32_bf16(af[i], bf[j], acc[i][j], 0, 0, 0);
    }
  }

  int fl = 0;
  if (MODE != 0) fl = *flagp;
  #pragma unroll
  for (int i = 0; i < 2; i++){
    int row_l = wr * 32 + i * 16 + quad * 4;
    #pragma unroll
    for (int j = 0; j < NJ; j++){
      int col = n0 + wc * (BN / 2) + j * 16 + lane15;
      float b = bias[col];
      #pragma unroll
      for (int r = 0; r < 4; r++){
        float v = acc[i][j][r] + b;
        long row = m0 + row_l + r;
        if (MODE == 0){
          outb[row * N + col] = f2bf(fast_tanh(v));
        } else if (MODE == 1){
          long idx = row * 128 + col;
          outf[idx] = v;
          ushort_t bb = f2bf(v);
          outb[idx] = bb;
          if (fl) ((ushort_t*)dout)[dout_off + idx] = bb;
          else    ((float*)dout)[dout_off + idx] = v;
        } else {
          long idx = row * N + col;
          if (fl) ((ushort_t*)dout)[dout_off + idx] = f2bf(v);
          else    ((float*)dout)[dout_off + idx] = v;
        }
      }
    }
  }
}

// =====================================================================
// generic 128x128 MFMA GEMM, BK=32. Kept for MODE 3 (VQ scores):
// acc - 0.5*enorm[col], per-row argmax over the 128-col tile. [N=1024]
// =====================================================================
template<int MODE>
__global__ __launch_bounds__(256)
void k_gemm(const ushort_t* __restrict__ A, const ushort_t* __restrict__ Bt,
            const float* __restrict__ bias, int N, int K,
            ushort_t* __restrict__ outb, float* __restrict__ outf,
            void* __restrict__ dout, long dout_off,
            const float* __restrict__ enorm,
            float* __restrict__ cand_v, int* __restrict__ cand_i,
            const int* __restrict__ flagp)
{
  __shared__ __align__(16) ushort_t As[128 * 32];
  __shared__ __align__(16) ushort_t Bs[128 * 32];
  const int tid = threadIdx.x;
  const int w = tid >> 6, lane = tid & 63;
  const int lane15 = lane & 15, quad = lane >> 4;
  const int wr = w >> 1, wc = w & 1;

  const int nx = N >> 7;
  const int lnx = __builtin_ctz(nx);
  const int f = blockIdx.x;
  const int j8 = f & 7, s = f >> 3;
  const int n_idx = s & (nx - 1);
  const int m_idx = ((s >> lnx) << 3) | j8;
  const long m0 = (long)m_idx * 128;
  const int n0 = n_idx * 128;

  const int lrow = lane >> 2;
  const int lk8  = (((lane & 3) ^ ((lane >> 3) & 3)) * 8);
  const int sw   = (lane15 >> 1) & 3;

  f32x4 acc[4][4];
  #pragma unroll
  for (int i = 0; i < 4; i++)
    #pragma unroll
    for (int j = 0; j < 4; j++) acc[i][j] = (f32x4){0.f, 0.f, 0.f, 0.f};

  const int nk = K >> 5;
  for (int kb = 0; kb < nk; kb++){
    const int k0 = kb << 5;
    __syncthreads();
    #pragma unroll
    for (int ss = 0; ss < 2; ss++){
      int m = w * 32 + ss * 16 + lrow;
      async16(A + ((m0 + m) * K + k0 + lk8), &As[(w * 32 + ss * 16) * 32]);
    }
    #pragma unroll
    for (int ss = 0; ss < 2; ss++){
      int n = w * 32 + ss * 16 + lrow;
      async16(Bt + ((long)(n0 + n) * K + k0 + lk8), &Bs[(w * 32 + ss * 16) * 32]);
    }
    __builtin_amdgcn_s_waitcnt(0);
    __syncthreads();

    bf16x8 af[4], bf[4];
    #pragma unroll
    for (int i = 0; i < 4; i++)
      af[i] = *(const bf16x8*)&As[(wr * 64 + i * 16 + lane15) * 32 + ((quad ^ sw) * 8)];
    #pragma unroll
    for (int j = 0; j < 4; j++)
      bf[j] = *(const bf16x8*)&Bs[(wc * 64 + j * 16 + lane15) * 32 + ((quad ^ sw) * 8)];
    #pragma unroll
    for (int i = 0; i < 4; i++)
      #pragma unroll
      for (int j = 0; j < 4; j++)
        acc[i][j] = __builtin_amdgcn_mfma_f32_16x16x32_bf16(af[i], bf[j], acc[i][j], 0, 0, 0);
  }

  { // MODE 3 only (other modes routed to k_gemm64)
    float bestv[16]; int bestc[16];
    #pragma unroll
    for (int i = 0; i < 4; i++){
      #pragma unroll
      for (int r = 0; r < 4; r++){
        float best = -1e30f; int bcol = 0;
        #pragma unroll
        for (int j = 0; j < 4; j++){
          int col = n0 + wc * 64 + j * 16 + lane15;
          float v = acc[i][j][r] - 0.5f * enorm[col];
          if (v > best){ best = v; bcol = col; }
        }
        #pragma unroll
        for (int off = 1; off < 16; off <<= 1){
          float ov = __shfl_xor(best, off, 64);
          int   oc = __shfl_xor(bcol, off, 64);
          if (ov > best || (ov == best && oc < bcol)){ best = ov; bcol = oc; }
        }
        bestv[i * 4 + r] = best; bestc[i * 4 + r] = bcol;
      }
    }
    __syncthreads();
    float* lv = (float*)As;
    int*   li = (int*)Bs;
    #pragma unroll
    for (int i = 0; i < 4; i++)
      #pragma unroll
      for (int r = 0; r < 4; r++){
        int row_l = wr * 64 + i * 16 + quad * 4 + r;
        if (lane15 == 0){ lv[row_l * 2 + wc] = bestv[i * 4 + r]; li[row_l * 2 + wc] = bestc[i * 4 + r]; }
      }
    __syncthreads();
    if (tid < 128){
      float v0 = lv[tid * 2], v1 = lv[tid * 2 + 1];
      int   c0 = li[tid * 2], c1 = li[tid * 2 + 1];
      float bv; int bc;
      if (v1 > v0 || (v1 == v0 && c1 < c0)){ bv = v1; bc = c1; } else { bv = v0; bc = c0; }
      long row = m0 + tid;
      cand_v[row * 8 + n_idx] = bv;
      cand_i[row * 8 + n_idx] = bc;
    }
  }
}

// =====================================================================
// VQ finalize. grid 16384, block 256 (2 rows / block)
// =====================================================================
__global__ __launch_bounds__(256)
void k_vqfin(const float* __restrict__ cand_v, const int* __restrict__ cand_i,
             const float* __restrict__ zf, const ushort_t* __restrict__ embb,
             ushort_t* __restrict__ qb, void* __restrict__ dout, long zq_off,
             float* __restrict__ loss_part, const int* __restrict__ flagp)
{
  int f = *flagp;
  long row = (long)blockIdx.x * 2 + (threadIdx.x >> 7);
  int d = threadIdx.x & 127;
  float best = -1e30f; int bi = 0;
  #pragma unroll
  for (int nb = 0; nb < 8; nb++){
    float v = cand_v[row * 8 + nb]; int c = cand_i[row * 8 + nb];
    if (v > best || (v == best && c < bi)){ best = v; bi = c; }
  }
  ushort_t qbits = embb[(long)bi * LATENT + d];
  float q = bf2f(qbits);
  long idx = row * LATENT + d;
  qb[idx] = qbits;
  if (f) ((ushort_t*)dout)[zq_off + idx] = qbits;
  else   ((float*)dout)[zq_off + idx] = q;
  float diff = zf[idx] - q;
  float p = diff * diff;
  #pragma unroll
  for (int off = 32; off; off >>= 1) p += __shfl_down(p, off, 64);
  __shared__ float red[4];
  if ((threadIdx.x & 63) == 0) red[threadIdx.x >> 6] = p;
  __syncthreads();
  if (threadIdx.x == 0) loss_part[blockIdx.x] = red[0] + red[1] + red[2] + red[3];
}

__global__ __launch_bounds__(256)
void k_lossfin(const float* __restrict__ loss_part, void* __restrict__ dout,
               long off, const int* __restrict__ flagp){
  __shared__ float red[4];
  float s = 0.f;
  for (int i = threadIdx.x; i < BB / 2; i += 256) s += loss_part[i];
  #pragma unroll
  for (int o = 32; o; o >>= 1) s += __shfl_down(s, o, 64);
  if ((threadIdx.x & 63) == 0) red[threadIdx.x >> 6] = s;
  __syncthreads();
  if (threadIdx.x == 0){
    float v = 1.25f * (red[0] + red[1] + red[2] + red[3]) / (float)((long)BB * LATENT);
    if (*flagp) ((ushort_t*)dout)[off] = f2bf(v);
    else        ((float*)dout)[off] = v;
  }
}

// =====================================================================
extern "C" void kernel_launch(void* const* d_in, const int* in_sizes, int n_in,
                              void* d_out, int out_size, void* d_ws, size_t ws_size,
                              hipStream_t stream)
{
  (void)in_sizes; (void)n_in; (void)out_size; (void)ws_size;
  const void* action = d_in[1];
  const void* eW0 = d_in[2];  const void* eb0 = d_in[3];
  const void* eW1 = d_in[4];  const void* eb1 = d_in[5];
  const void* eW2 = d_in[6];  const void* eb2 = d_in[7];
  const void* emb = d_in[8];
  const void* dW0 = d_in[9];  const void* db0 = d_in[10];
  const void* dW1 = d_in[11]; const void* db1 = d_in[12];
  const void* dW2 = d_in[13]; const void* db2 = d_in[14];

  char* ws = (char*)d_ws;
  size_t off = 0;
  auto alloc = [&](size_t bytes)->char*{
    char* p = ws + off; off += bytes; off = (off + 255) & ~((size_t)255); return p;
  };
  int*      flag     = (int*)  alloc(4);
  float*    biasf    = (float*)alloc(6 * 1024 * 4);
  float*    enorm    = (float*)alloc(KCODES * 4);
  ushort_t* eW0t = (ushort_t*)alloc((size_t)HID * INDIM * 2);
  ushort_t* eW1t = (ushort_t*)alloc((size_t)HID * HID * 2);
  ushort_t* eW2t = (ushort_t*)alloc((size_t)LATENT * HID * 2);
  ushort_t* embb = (ushort_t*)alloc((size_t)KCODES * LATENT * 2);
  ushort_t* dW0t = (ushort_t*)alloc((size_t)HID * LATENT * 2);
  ushort_t* dW1t = (ushort_t*)alloc((size_t)HID * HID * 2);
  ushort_t* dW2t = (ushort_t*)alloc((size_t)INDIM * HID * 2);
  ushort_t* act0 = (ushort_t*)alloc((size_t)BB * INDIM * 2);
  ushort_t* hA   = (ushort_t*)alloc((size_t)BB * HID * 2);
  ushort_t* hB   = (ushort_t*)alloc((size_t)BB * HID * 2);
  float*    zf32 = (float*)   alloc((size_t)BB * LATENT * 4);
  ushort_t* zb16 = (ushort_t*)alloc((size_t)BB * LATENT * 2);
  ushort_t* qb16 = (ushort_t*)alloc((size_t)BB * LATENT * 2);
  float*    cand_v = (float*) alloc((size_t)BB * 8 * 4);
  int*      cand_i = (int*)   alloc((size_t)BB * 8 * 4);
  float*    loss_part = (float*)alloc((size_t)(BB / 2) * 4);

  const long z_off  = (long)BB * INDIM;
  const long zq_off = z_off + (long)BB * LATENT;
  const long l_off  = zq_off + (long)BB * LATENT;

  // ---- prep (merged: 4 launches, was 6) ----
  k_sniff<<<1, 64, 0, stream>>>((const ushort_t*)action, flag);
  {
    const int A8 = BB * INDIM / 8, E8 = KCODES * LATENT / 8;
    int total = A8 + E8 + 6144;
    k_prep<<<(total + 255) / 256, 256, 0, stream>>>(action, act0, emb, embb,
        eb0, eb1, eb2, db0, db1, db2, biasf, flag);
  }
  k_tcvt6<<<2816, 256, 0, stream>>>(eW0, eW0t, eW1, eW1t, eW2, eW2t,
                                    dW0, dW0t, dW1, dW1t, dW2, dW2t, flag);
  k_enorm<<<4, 256, 0, stream>>>(embb, enorm);

  // ---- encoder ----
  k_gemm64<0, 256><<<2048, 256, 0, stream>>>(act0, eW0t, biasf + 0, 1024, INDIM,
      hA, nullptr, nullptr, 0, flag);                                          // K=256
  k_gemmw<<<1024, 256, 0, stream>>>(hA, eW1t, biasf + 1024, HID, hB);          // K=1024
  k_gemm64<1, 128><<<512, 256, 0, stream>>>(hB, eW2t, biasf + 2048, 128, HID,
      zb16, zf32, d_out, z_off, flag);                                         // z

  // ---- VQ ----
  k_gemm<3><<<8 * 256, 256, 0, stream>>>(zb16, embb, nullptr, KCODES, LATENT,
      nullptr, nullptr, nullptr, 0, enorm, cand_v, cand_i, flag);
  k_vqfin<<<BB / 2, 256, 0, stream>>>(cand_v, cand_i, zf32, embb, qb16, d_out, zq_off,
      loss_part, flag);

  // ---- decoder ----
  k_gemm64<0, 256><<<2048, 256, 0, stream>>>(qb16, dW0t, biasf + 3072, 1024, LATENT,
      hA, nullptr, nullptr, 0, flag);                                          // K=128
  k_gemmw<<<1024, 256, 0, stream>>>(hA, dW1t, biasf + 4096, HID, hB);          // K=1024
  k_gemm64<2, 256><<<512, 256, 0, stream>>>(hB, dW2t, biasf + 5120, 256, HID,
      nullptr, nullptr, d_out, 0, flag);                                       // recon

  k_lossfin<<<1, 256, 0, stream>>>(loss_part, d_out, l_off, flag);
}

// Round 3
// 427.685 us; speedup vs baseline: 1.2585x; 1.0820x over previous
//
#include <hip/hip_runtime.h>
#include <stdint.h>
#include <math.h>

#define DEVI __device__ __forceinline__
typedef unsigned short ushort_t;
typedef __attribute__((ext_vector_type(8))) __bf16 bf16x8;
typedef __attribute__((ext_vector_type(4))) float f32x4;

// ---------- scalar bf16 helpers (RNE, matches HW/harness encoding) ----------
DEVI float bf2f(ushort_t b){ union{uint32_t u; float f;} c; c.u = ((uint32_t)b) << 16; return c.f; }
DEVI ushort_t f2bf(float f){ union{float f; uint32_t u;} c; c.f = f; uint32_t u = c.u;
                             u += 0x7fffu + ((u >> 16) & 1u); return (ushort_t)(u >> 16); }

// fast tanh: 1 - 2/(exp2(2*log2e*x)+1). ~5 VALU ops, saturates correctly.
DEVI float fast_tanh(float x){
  float t = __builtin_amdgcn_exp2f(x * 2.8853900817779268f);
  return 1.0f - 2.0f * __builtin_amdgcn_rcpf(t + 1.0f);
}

// ---------- async global->LDS (16B per lane, dest = wave-uniform base + lane*16) ----------
DEVI void async16(const ushort_t* g, ushort_t* l){
  __builtin_amdgcn_global_load_lds((const __attribute__((address_space(1))) void*)g,
                                   (__attribute__((address_space(3))) void*)l, 16, 0, 0);
}

// ---------- problem constants ----------
#define BB 32768
#define INDIM 256
#define LATENT 128
#define HID 1024
#define KCODES 1024

// =====================================================================
// dtype sniffer: flag = 1 -> buffers are bf16 ; flag = 0 -> fp32
// =====================================================================
__global__ void k_sniff(const ushort_t* __restrict__ act, int* flag){
  if (threadIdx.x == 0){
    int bad = 0;
    for (int i = 0; i < 256; i++){
      float v = bf2f(act[i]);
      float a = fabsf(v);
      if (!(a <= 16.0f) || (a > 0.0f && a < 9.5e-7f)) bad++;
    }
    flag[0] = (bad >= 8) ? 0 : 1;
  }
}

// merged prep: action->bf16, emb->bf16, 6 biases->fp32, enorm, ONE launch.
// segments: A8=BB*INDIM/8, E8=KCODES*LATENT/8, 6144 bias slots, 1024 enorm.
__global__ void k_prep(const void* __restrict__ act_src, ushort_t* __restrict__ act_dst,
                       const void* __restrict__ emb_src, ushort_t* __restrict__ emb_dst,
                       const void* b0, const void* b1, const void* b2,
                       const void* b3, const void* b4, const void* b5,
                       float* __restrict__ biasf, float* __restrict__ enorm,
                       const int* __restrict__ flagp){
  const int f = *flagp;
  const int A8 = BB * INDIM / 8;
  const int E8 = KCODES * LATENT / 8;
  int i = blockIdx.x * blockDim.x + threadIdx.x;
  if (i < A8 + E8){
    const void* src; ushort_t* dst; int k;
    if (i < A8){ src = act_src; dst = act_dst; k = i; }
    else       { src = emb_src; dst = emb_dst; k = i - A8; }
    if (f){
      ((uint4*)dst)[k] = ((const uint4*)src)[k];
    } else {
      const float* s = (const float*)src + (size_t)k * 8;
      ushort_t o[8];
      #pragma unroll
      for (int j = 0; j < 8; j++) o[j] = f2bf(s[j]);
      ((uint4*)dst)[k] = *(const uint4*)o;
    }
  } else {
    int k = i - A8 - E8;
    if (k < 6144){
      int seg = k >> 10, off = k & 1023;
      const void* sp; int n;
      switch (seg){
        case 0: sp = b0; n = 1024; break;
        case 1: sp = b1; n = 1024; break;
        case 2: sp = b2; n = 128;  break;
        case 3: sp = b3; n = 1024; break;
        case 4: sp = b4; n = 1024; break;
        default: sp = b5; n = 256; break;
      }
      if (off < n)
        biasf[seg * 1024 + off] = f ? bf2f(((const ushort_t*)sp)[off]) : ((const float*)sp)[off];
    } else if (k < 6144 + KCODES){
      // ||e_c||^2 from the bf16-rounded codebook (bit-identical to old k_enorm)
      int c = k - 6144;
      float s = 0.f;
      if (f){
        const ushort_t* e = (const ushort_t*)emb_src + (long)c * LATENT;
        for (int d = 0; d < LATENT; d++){ float v = bf2f(e[d]); s += v * v; }
      } else {
        const float* e = (const float*)emb_src + (long)c * LATENT;
        for (int d = 0; d < LATENT; d++){ float v = bf2f(f2bf(e[d])); s += v * v; }
      }
      enorm[c] = s;
    }
  }
}

// all 6 weight transposes in ONE launch. src[R][C] -> dst[C][R] bf16.
// grid 2816 x 256: seg tile counts 256,1024,128,128,1024,256.
__global__ void k_tcvt6(const void* s0, ushort_t* d0, const void* s1, ushort_t* d1,
                        const void* s2, ushort_t* d2, const void* s3, ushort_t* d3,
                        const void* s4, ushort_t* d4, const void* s5, ushort_t* d5,
                        const int* __restrict__ flagp){
  __shared__ ushort_t tile[32][33];
  int f = *flagp;
  int t = blockIdx.x;
  const void* src; ushort_t* dst; int R, C, lcx;
  if (t < 256)      { src=s0; dst=d0; R=256;  C=1024; lcx=5; }
  else if (t < 1280){ src=s1; dst=d1; R=1024; C=1024; lcx=5; t-=256;  }
  else if (t < 1408){ src=s2; dst=d2; R=1024; C=128;  lcx=2; t-=1280; }
  else if (t < 1536){ src=s3; dst=d3; R=128;  C=1024; lcx=5; t-=1408; }
  else if (t < 2560){ src=s4; dst=d4; R=1024; C=1024; lcx=5; t-=1536; }
  else              { src=s5; dst=d5; R=1024; C=256;  lcx=3; t-=2560; }
  int bx = t & ((C >> 5) - 1), by = t >> lcx;
  int tx = threadIdx.x & 31, ty = threadIdx.x >> 5;
  int c = bx * 32 + tx;
  #pragma unroll
  for (int ii = 0; ii < 4; ii++){
    int r = by * 32 + ty + ii * 8;
    long idx = (long)r * C + c;
    tile[ty + ii * 8][tx] = f ? ((const ushort_t*)src)[idx] : f2bf(((const float*)src)[idx]);
  }
  __syncthreads();
  #pragma unroll
  for (int ii = 0; ii < 4; ii++){
    int cc = bx * 32 + ty + ii * 8;
    dst[(long)cc * R + by * 32 + tx] = tile[tx][ty + ii * 8];
  }
}

// =====================================================================
// WIDE MFMA GEMM (N==1024): C = tanh(A[M,K] @ Bt[N,K]^T + b)
// 128x256 block tile, BK=64. Proven ~75us / 40% MfmaUtil on K=1024.
// True regs ~108 VGPR + 128 acc => 2 blocks/CU; cross-block TLP hides
// the per-tile drain. This is the m97-structure ceiling (~940 TF).
// =====================================================================
__global__ __launch_bounds__(256, 2)
void k_gemmw(const ushort_t* __restrict__ A, const ushort_t* __restrict__ Bt,
             const float* __restrict__ bias, int K,
             ushort_t* __restrict__ outb)
{
  const int N = 1024;
  __shared__ __align__(16) ushort_t As[128 * 64];   // 16 KB
  __shared__ __align__(16) ushort_t Bs[256 * 64];   // 32 KB
  const int tid = threadIdx.x;
  const int w = tid >> 6, lane = tid & 63;
  const int lane15 = lane & 15, quad = lane >> 4;
  const int wr = w >> 1, wc = w & 1;

  // ---- XCD-locality swizzle: 4 n-tiles (256 wide), 256 m-tiles ----
  const int f = blockIdx.x;
  const int j8 = f & 7, s = f >> 3;
  const int n_idx = s & 3;
  const int m_idx = ((s >> 2) << 3) | j8;
  const long m0 = (long)m_idx * 128;
  const int n0 = n_idx * 256;

  // staging lane decomposition: r = lane>>3 (8 rows/shot), c = lane&7
  const int lrow = lane >> 3;
  const int lk8  = (((lane & 7) ^ (lrow & 7)) * 8);   // XOR-swizzled k-chunk
  const int rx   = lane15 & 7;

  f32x4 acc[4][8];
  #pragma unroll
  for (int i = 0; i < 4; i++)
    #pragma unroll
    for (int j = 0; j < 8; j++) acc[i][j] = (f32x4){0.f, 0.f, 0.f, 0.f};

  const int nk = K >> 6;
  for (int kb = 0; kb < nk; kb++){
    const int k0 = kb << 6;
    __syncthreads();
    #pragma unroll
    for (int a = 0; a < 4; a++){
      int m = w * 32 + a * 8 + lrow;
      async16(A + ((m0 + m) * K + k0 + lk8), &As[(w * 32 + a * 8) * 64]);
    }
    #pragma unroll
    for (int b = 0; b < 8; b++){
      int n = w * 64 + b * 8 + lrow;
      async16(Bt + ((long)(n0 + n) * K + k0 + lk8), &Bs[(w * 64 + b * 8) * 64]);
    }
    __builtin_amdgcn_s_waitcnt(0);
    __syncthreads();

    #pragma unroll
    for (int h = 0; h < 2; h++){
      bf16x8 af[4], bf[8];
      #pragma unroll
      for (int i = 0; i < 4; i++){
        int rho = wr * 64 + i * 16 + lane15;
        af[i] = *(const bf16x8*)&As[rho * 64 + ((((h << 2) | quad) ^ rx) * 8)];
      }
      #pragma unroll
      for (int j = 0; j < 8; j++){
        int rho = wc * 128 + j * 16 + lane15;
        bf[j] = *(const bf16x8*)&Bs[rho * 64 + ((((h << 2) | quad) ^ rx) * 8)];
      }
      #pragma unroll
      for (int i = 0; i < 4; i++)
        #pragma unroll
        for (int j = 0; j < 8; j++)
          acc[i][j] = __builtin_amdgcn_mfma_f32_16x16x32_bf16(af[i], bf[j], acc[i][j], 0, 0, 0);
    }
  }

  #pragma unroll
  for (int i = 0; i < 4; i++){
    int row_l = wr * 64 + i * 16 + quad * 4;
    #pragma unroll
    for (int j = 0; j < 8; j++){
      int col = n0 + wc * 128 + j * 16 + lane15;
      float b = bias[col];
      #pragma unroll
      for (int r = 0; r < 4; r++){
        float v = fast_tanh(acc[i][j][r] + b);
        outb[(m0 + row_l + r) * N + col] = f2bf(v);
      }
    }
  }
}

// =====================================================================
// SLIM MFMA GEMM: 64xBN block tile, BK=64, 4 waves, wave = 32 x BN/2.
// MODE 0: tanh -> bf16 buffer outb (N-stride cols)          [L0 layers]
// MODE 1: z: fp32 buf + bf16 buf + d_out (flag dtype)       [N=BN=128]
// MODE 2: recon: d_out only (flag dtype)                    [N=BN=256]
// =====================================================================
template<int MODE, int BN>
__global__ __launch_bounds__(256)
void k_gemm64(const ushort_t* __restrict__ A, const ushort_t* __restrict__ Bt,
              const float* __restrict__ bias, int N, int K,
              ushort_t* __restrict__ outb, float* __restrict__ outf,
              void* __restrict__ dout, long dout_off,
              const int* __restrict__ flagp)
{
  constexpr int NJ = BN / 32;                 // j-frags per wave: 8 (BN=256) / 4 (BN=128)
  __shared__ __align__(16) ushort_t As[64 * 64];    // 8 KB
  __shared__ __align__(16) ushort_t Bs[BN * 64];    // 32/16 KB
  const int tid = threadIdx.x;
  const int w = tid >> 6, lane = tid & 63;
  const int lane15 = lane & 15, quad = lane >> 4;
  const int wr = w >> 1, wc = w & 1;

  const int nx = N / BN;                      // 1 or 4
  const int lnx = __builtin_ctz(nx);
  const int f = blockIdx.x;
  const int j8 = f & 7, s = f >> 3;
  const int n_idx = s & (nx - 1);
  const int m_idx = ((s >> lnx) << 3) | j8;
  const long m0 = (long)m_idx * 64;
  const int n0 = n_idx * BN;

  const int lrow = lane >> 3;
  const int lk8  = (((lane & 7) ^ lrow) << 3);
  const int rx   = lane15 & 7;

  f32x4 acc[2][NJ];
  #pragma unroll
  for (int i = 0; i < 2; i++)
    #pragma unroll
    for (int j = 0; j < NJ; j++) acc[i][j] = (f32x4){0.f, 0.f, 0.f, 0.f};

  const int nk = K >> 6;
  for (int kb = 0; kb < nk; kb++){
    const int k0 = kb << 6;
    __syncthreads();
    #pragma unroll
    for (int a = 0; a < 2; a++){
      int m = w * 16 + a * 8 + lrow;
      async16(A + ((m0 + m) * K + k0 + lk8), &As[(w * 16 + a * 8) * 64]);
    }
    #pragma unroll
    for (int b = 0; b < NJ; b++){
      int n = w * (BN / 4) + b * 8 + lrow;
      async16(Bt + ((long)(n0 + n) * K + k0 + lk8), &Bs[(w * (BN / 4) + b * 8) * 64]);
    }
    __builtin_amdgcn_s_waitcnt(0);
    __syncthreads();

    #pragma unroll
    for (int h = 0; h < 2; h++){
      bf16x8 af[2], bf[NJ];
      #pragma unroll
      for (int i = 0; i < 2; i++){
        int rho = wr * 32 + i * 16 + lane15;
        af[i] = *(const bf16x8*)&As[rho * 64 + ((((h << 2) | quad) ^ rx) * 8)];
      }
      #pragma unroll
      for (int j = 0; j < NJ; j++){
        int rho = wc * (BN / 2) + j * 16 + lane15;
        bf[j] = *(const bf16x8*)&Bs[rho * 64 + ((((h << 2) | quad) ^ rx) * 8)];
      }
      #pragma unroll
      for (int i = 0; i < 2; i++)
        #pragma unroll
        for (int j = 0; j < NJ; j++)
          acc[i][j] = __builtin_amdgcn_mfma_f32_16x16x32_bf16(af[i], bf[j], acc[i][j], 0, 0, 0);
    }
  }

  int fl = 0;
  if (MODE != 0) fl = *flagp;
  #pragma unroll
  for (int i = 0; i < 2; i++){
    int row_l = wr * 32 + i * 16 + quad * 4;
    #pragma unroll
    for (int j = 0; j < NJ; j++){
      int col = n0 + wc * (BN / 2) + j * 16 + lane15;
      float b = bias[col];
      #pragma unroll
      for (int r = 0; r < 4; r++){
        float v = acc[i][j][r] + b;
        long row = m0 + row_l + r;
        if (MODE == 0){
          outb[row * N + col] = f2bf(fast_tanh(v));
        } else if (MODE == 1){
          long idx = row * 128 + col;
          outf[idx] = v;
          ushort_t bb = f2bf(v);
          outb[idx] = bb;
          if (fl) ((ushort_t*)dout)[dout_off + idx] = bb;
          else    ((float*)dout)[dout_off + idx] = v;
        } else {
          long idx = row * N + col;
          if (fl) ((ushort_t*)dout)[dout_off + idx] = f2bf(v);
          else    ((float*)dout)[dout_off + idx] = v;
        }
      }
    }
  }
}

// =====================================================================
// FUSED VQ: scores + argmax + gather + zq write + loss partial, ONE kernel.
// grid 512 x 256: each block owns 64 rows. z-tile (64x128) staged to LDS
// once; 8 codebook tiles (128x128) streamed through LDS; running argmax
// per lane (same MFMA k-order as before => bit-identical scores/indices).
// Replaces k_gemm<3> (2048 blocks) + k_vqfin (16384 blocks) + cand arrays.
// =====================================================================
__global__ __launch_bounds__(256)
void k_vq(const ushort_t* __restrict__ zb, const float* __restrict__ zf,
          const ushort_t* __restrict__ embb, const float* __restrict__ enorm,
          ushort_t* __restrict__ qb, void* __restrict__ dout, long zq_off,
          float* __restrict__ loss_part, const int* __restrict__ flagp)
{
  __shared__ __align__(16) ushort_t zt[64 * 128];    // 16 KB (persistent)
  __shared__ __align__(16) ushort_t et[128 * 128];   // 32 KB (streamed)
  __shared__ float lv[64][4];
  __shared__ int   li[64][4];
  __shared__ int   bi[64];
  __shared__ float red[4];

  const int tid = threadIdx.x;
  const int w = tid >> 6, lane = tid & 63;
  const int lane15 = lane & 15, quad = lane >> 4;
  const long m0 = (long)blockIdx.x * 64;

  // staging: each shot = 4 rows x 16 chunks of 8 elems (64 lanes x 16B).
  // slot (r, c) holds global chunk c ^ (r&15); readers XOR identically.
  const int srow = lane >> 4;          // row within shot (0..3)
  const int schk = lane & 15;          // chunk slot (0..15)

  // z-tile: 16 rows per wave, 4 shots
  #pragma unroll
  for (int s4 = 0; s4 < 4; s4++){
    int r = w * 16 + s4 * 4 + srow;
    async16(zb + (m0 + r) * 128 + ((schk ^ (r & 15)) * 8), &zt[(w * 16 + s4 * 4) * 128]);
  }
  // emb tile 0: 32 rows per wave, 8 shots
  #pragma unroll
  for (int s8 = 0; s8 < 8; s8++){
    int r = w * 32 + s8 * 4 + srow;
    async16(embb + (long)r * 128 + ((schk ^ (r & 15)) * 8), &et[(w * 32 + s8 * 4) * 128]);
  }
  __builtin_amdgcn_s_waitcnt(0);
  __syncthreads();

  float bestv[16];
  int   bestc[16];
  #pragma unroll
  for (int u = 0; u < 16; u++){ bestv[u] = -1e30f; bestc[u] = 0; }

  for (int t = 0; t < 8; t++){
    f32x4 acc[4][2];
    #pragma unroll
    for (int i = 0; i < 4; i++){
      acc[i][0] = (f32x4){0.f, 0.f, 0.f, 0.f};
      acc[i][1] = (f32x4){0.f, 0.f, 0.f, 0.f};
    }
    #pragma unroll
    for (int ks = 0; ks < 4; ks++){
      bf16x8 af[4], bf[2];
      #pragma unroll
      for (int i = 0; i < 4; i++){
        int rho = i * 16 + lane15;
        af[i] = *(const bf16x8*)&zt[rho * 128 + ((((ks << 2) | quad) ^ (rho & 15)) * 8)];
      }
      #pragma unroll
      for (int j = 0; j < 2; j++){
        int rho = w * 32 + j * 16 + lane15;
        bf[j] = *(const bf16x8*)&et[rho * 128 + ((((ks << 2) | quad) ^ (rho & 15)) * 8)];
      }
      #pragma unroll
      for (int i = 0; i < 4; i++)
        #pragma unroll
        for (int j = 0; j < 2; j++)
          acc[i][j] = __builtin_amdgcn_mfma_f32_16x16x32_bf16(af[i], bf[j], acc[i][j], 0, 0, 0);
    }
    // fold into running best (codes ascending: j then t => ties keep lowest)
    #pragma unroll
    for (int i = 0; i < 4; i++)
      #pragma unroll
      for (int r = 0; r < 4; r++)
        #pragma unroll
        for (int j = 0; j < 2; j++){
          int code = t * 128 + w * 32 + j * 16 + lane15;
          float v = acc[i][j][r] - 0.5f * enorm[code];
          int u = i * 4 + r;
          if (v > bestv[u]){ bestv[u] = v; bestc[u] = code; }
        }
    if (t < 7){
      __syncthreads();
      #pragma unroll
      for (int s8 = 0; s8 < 8; s8++){
        int r = w * 32 + s8 * 4 + srow;
        async16(embb + ((long)(t + 1) * 128 + r) * 128 + ((schk ^ (r & 15)) * 8),
                &et[(w * 32 + s8 * 4) * 128]);
      }
      __builtin_amdgcn_s_waitcnt(0);
      __syncthreads();
    }
  }

  // per-wave argmax (16-lane groups hold 16 distinct codes per (i,r))
  #pragma unroll
  for (int i = 0; i < 4; i++)
    #pragma unroll
    for (int r = 0; r < 4; r++){
      float bv = bestv[i * 4 + r]; int bc = bestc[i * 4 + r];
      #pragma unroll
      for (int off = 1; off < 16; off <<= 1){
        float ov = __shfl_xor(bv, off, 64);
        int   oc = __shfl_xor(bc, off, 64);
        if (ov > bv || (ov == bv && oc < bc)){ bv = ov; bc = oc; }
      }
      if (lane15 == 0){
        int row_l = i * 16 + quad * 4 + r;
        lv[row_l][w] = bv; li[row_l][w] = bc;
      }
    }
  __syncthreads();
  // cross-wave combine (w ascending = code ascending; tie keeps lowest)
  if (tid < 64){
    float bv = lv[tid][0]; int bc = li[tid][0];
    #pragma unroll
    for (int ww = 1; ww < 4; ww++){
      float ov = lv[tid][ww]; int oc = li[tid][ww];
      if (ov > bv || (ov == bv && oc < bc)){ bv = ov; bc = oc; }
    }
    bi[tid] = bc;
  }
  __syncthreads();

  // finalize: gather emb[best], write qb16 + zq, accumulate loss partial
  const int fl = *flagp;
  const int d = tid & 127;
  const int rb = tid >> 7;       // 0..1
  float p = 0.f;
  for (int it = 0; it < 32; it++){
    int row = rb * 32 + it;
    int code = bi[row];
    ushort_t qbits = embb[(long)code * LATENT + d];
    float qv = bf2f(qbits);
    long idx = (m0 + row) * LATENT + d;
    qb[idx] = qbits;
    if (fl) ((ushort_t*)dout)[zq_off + idx] = qbits;
    else    ((float*)dout)[zq_off + idx] = qv;
    float diff = zf[idx] - qv;
    p += diff * diff;
  }
  #pragma unroll
  for (int off = 32; off; off >>= 1) p += __shfl_down(p, off, 64);
  if ((tid & 63) == 0) red[tid >> 6] = p;
  __syncthreads();
  if (tid == 0) loss_part[blockIdx.x] = red[0] + red[1] + red[2] + red[3];
}

__global__ __launch_bounds__(256)
void k_lossfin(const float* __restrict__ loss_part, void* __restrict__ dout,
               long off, const int* __restrict__ flagp){
  __shared__ float red[4];
  float s = 0.f;
  for (int i = threadIdx.x; i < 512; i += 256) s += loss_part[i];
  #pragma unroll
  for (int o = 32; o; o >>= 1) s += __shfl_down(s, o, 64);
  if ((threadIdx.x & 63) == 0) red[threadIdx.x >> 6] = s;
  __syncthreads();
  if (threadIdx.x == 0){
    float v = 1.25f * (red[0] + red[1] + red[2] + red[3]) / (float)((long)BB * LATENT);
    if (*flagp) ((ushort_t*)dout)[off] = f2bf(v);
    else        ((float*)dout)[off] = v;
  }
}

// =====================================================================
extern "C" void kernel_launch(void* const* d_in, const int* in_sizes, int n_in,
                              void* d_out, int out_size, void* d_ws, size_t ws_size,
                              hipStream_t stream)
{
  (void)in_sizes; (void)n_in; (void)out_size; (void)ws_size;
  const void* action = d_in[1];
  const void* eW0 = d_in[2];  const void* eb0 = d_in[3];
  const void* eW1 = d_in[4];  const void* eb1 = d_in[5];
  const void* eW2 = d_in[6];  const void* eb2 = d_in[7];
  const void* emb = d_in[8];
  const void* dW0 = d_in[9];  const void* db0 = d_in[10];
  const void* dW1 = d_in[11]; const void* db1 = d_in[12];
  const void* dW2 = d_in[13]; const void* db2 = d_in[14];

  char* ws = (char*)d_ws;
  size_t off = 0;
  auto alloc = [&](size_t bytes)->char*{
    char* p = ws + off; off += bytes; off = (off + 255) & ~((size_t)255); return p;
  };
  int*      flag     = (int*)  alloc(4);
  float*    biasf    = (float*)alloc(6 * 1024 * 4);
  float*    enorm    = (float*)alloc(KCODES * 4);
  ushort_t* eW0t = (ushort_t*)alloc((size_t)HID * INDIM * 2);
  ushort_t* eW1t = (ushort_t*)alloc((size_t)HID * HID * 2);
  ushort_t* eW2t = (ushort_t*)alloc((size_t)LATENT * HID * 2);
  ushort_t* embb = (ushort_t*)alloc((size_t)KCODES * LATENT * 2);
  ushort_t* dW0t = (ushort_t*)alloc((size_t)HID * LATENT * 2);
  ushort_t* dW1t = (ushort_t*)alloc((size_t)HID * HID * 2);
  ushort_t* dW2t = (ushort_t*)alloc((size_t)INDIM * HID * 2);
  ushort_t* act0 = (ushort_t*)alloc((size_t)BB * INDIM * 2);
  ushort_t* hA   = (ushort_t*)alloc((size_t)BB * HID * 2);
  ushort_t* hB   = (ushort_t*)alloc((size_t)BB * HID * 2);
  float*    zf32 = (float*)   alloc((size_t)BB * LATENT * 4);
  ushort_t* zb16 = (ushort_t*)alloc((size_t)BB * LATENT * 2);
  ushort_t* qb16 = (ushort_t*)alloc((size_t)BB * LATENT * 2);
  float*    loss_part = (float*)alloc((size_t)512 * 4);

  const long z_off  = (long)BB * INDIM;
  const long zq_off = z_off + (long)BB * LATENT;
  const long l_off  = zq_off + (long)BB * LATENT;

  // ---- prep (3 launches) ----
  k_sniff<<<1, 64, 0, stream>>>((const ushort_t*)action, flag);
  {
    const int A8 = BB * INDIM / 8, E8 = KCODES * LATENT / 8;
    int total = A8 + E8 + 6144 + KCODES;
    k_prep<<<(total + 255) / 256, 256, 0, stream>>>(action, act0, emb, embb,
        eb0, eb1, eb2, db0, db1, db2, biasf, enorm, flag);
  }
  k_tcvt6<<<2816, 256, 0, stream>>>(eW0, eW0t, eW1, eW1t, eW2, eW2t,
                                    dW0, dW0t, dW1, dW1t, dW2, dW2t, flag);

  // ---- encoder ----
  k_gemm64<0, 256><<<2048, 256, 0, stream>>>(act0, eW0t, biasf + 0, 1024, INDIM,
      hA, nullptr, nullptr, 0, flag);                                          // K=256
  k_gemmw<<<1024, 256, 0, stream>>>(hA, eW1t, biasf + 1024, HID, hB);          // K=1024
  k_gemm64<1, 128><<<512, 256, 0, stream>>>(hB, eW2t, biasf + 2048, 128, HID,
      zb16, zf32, d_out, z_off, flag);                                         // z

  // ---- VQ (fused: scores + argmax + gather + loss) ----
  k_vq<<<512, 256, 0, stream>>>(zb16, zf32, embb, enorm, qb16, d_out, zq_off,
      loss_part, flag);

  // ---- decoder ----
  k_gemm64<0, 256><<<2048, 256, 0, stream>>>(qb16, dW0t, biasf + 3072, 1024, LATENT,
      hA, nullptr, nullptr, 0, flag);                                          // K=128
  k_gemmw<<<1024, 256, 0, stream>>>(hA, dW1t, biasf + 4096, HID, hB);          // K=1024
  k_gemm64<2, 256><<<512, 256, 0, stream>>>(hB, dW2t, biasf + 5120, 256, HID,
      nullptr, nullptr, d_out, 0, flag);                                       // recon

  k_lossfin<<<1, 256, 0, stream>>>(loss_part, d_out, l_off, flag);
}

// Round 4
// 411.468 us; speedup vs baseline: 1.3081x; 1.0394x over previous
//
#include <hip/hip_runtime.h>
#include <stdint.h>
#include <math.h>

#define DEVI __device__ __forceinline__
typedef unsigned short ushort_t;
typedef __attribute__((ext_vector_type(8))) __bf16 bf16x8;
typedef __attribute__((ext_vector_type(4))) float f32x4;

// ---------- scalar bf16 helpers (RNE, matches HW/harness encoding) ----------
DEVI float bf2f(ushort_t b){ union{uint32_t u; float f;} c; c.u = ((uint32_t)b) << 16; return c.f; }
DEVI ushort_t f2bf(float f){ union{float f; uint32_t u;} c; c.f = f; uint32_t u = c.u;
                             u += 0x7fffu + ((u >> 16) & 1u); return (ushort_t)(u >> 16); }

// fast tanh: 1 - 2/(exp2(2*log2e*x)+1). ~5 VALU ops, saturates correctly.
DEVI float fast_tanh(float x){
  float t = __builtin_amdgcn_exp2f(x * 2.8853900817779268f);
  return 1.0f - 2.0f * __builtin_amdgcn_rcpf(t + 1.0f);
}

// ---------- async global->LDS (16B per lane, dest = wave-uniform base + lane*16) ----------
DEVI void async16(const ushort_t* g, ushort_t* l){
  __builtin_amdgcn_global_load_lds((const __attribute__((address_space(1))) void*)g,
                                   (__attribute__((address_space(3))) void*)l, 16, 0, 0);
}

// ---------- problem constants ----------
#define BB 32768
#define INDIM 256
#define LATENT 128
#define HID 1024
#define KCODES 1024

// =====================================================================
// dtype sniffer: flag = 1 -> buffers are bf16 ; flag = 0 -> fp32
// =====================================================================
__global__ void k_sniff(const ushort_t* __restrict__ act, int* flag){
  if (threadIdx.x == 0){
    int bad = 0;
    for (int i = 0; i < 256; i++){
      float v = bf2f(act[i]);
      float a = fabsf(v);
      if (!(a <= 16.0f) || (a > 0.0f && a < 9.5e-7f)) bad++;
    }
    flag[0] = (bad >= 8) ? 0 : 1;
  }
}

// merged prep: action->bf16, emb->bf16, 6 biases->fp32, enorm, ONE launch.
// segments: A8=BB*INDIM/8, E8=KCODES*LATENT/8, 6144 bias slots, 1024 enorm.
__global__ void k_prep(const void* __restrict__ act_src, ushort_t* __restrict__ act_dst,
                       const void* __restrict__ emb_src, ushort_t* __restrict__ emb_dst,
                       const void* b0, const void* b1, const void* b2,
                       const void* b3, const void* b4, const void* b5,
                       float* __restrict__ biasf, float* __restrict__ enorm,
                       const int* __restrict__ flagp){
  const int f = *flagp;
  const int A8 = BB * INDIM / 8;
  const int E8 = KCODES * LATENT / 8;
  int i = blockIdx.x * blockDim.x + threadIdx.x;
  if (i < A8 + E8){
    const void* src; ushort_t* dst; int k;
    if (i < A8){ src = act_src; dst = act_dst; k = i; }
    else       { src = emb_src; dst = emb_dst; k = i - A8; }
    if (f){
      ((uint4*)dst)[k] = ((const uint4*)src)[k];
    } else {
      const float* s = (const float*)src + (size_t)k * 8;
      ushort_t o[8];
      #pragma unroll
      for (int j = 0; j < 8; j++) o[j] = f2bf(s[j]);
      ((uint4*)dst)[k] = *(const uint4*)o;
    }
  } else {
    int k = i - A8 - E8;
    if (k < 6144){
      int seg = k >> 10, off = k & 1023;
      const void* sp; int n;
      switch (seg){
        case 0: sp = b0; n = 1024; break;
        case 1: sp = b1; n = 1024; break;
        case 2: sp = b2; n = 128;  break;
        case 3: sp = b3; n = 1024; break;
        case 4: sp = b4; n = 1024; break;
        default: sp = b5; n = 256; break;
      }
      if (off < n)
        biasf[seg * 1024 + off] = f ? bf2f(((const ushort_t*)sp)[off]) : ((const float*)sp)[off];
    } else if (k < 6144 + KCODES){
      // ||e_c||^2 from the bf16-rounded codebook (bit-identical to old k_enorm)
      int c = k - 6144;
      float s = 0.f;
      if (f){
        const ushort_t* e = (const ushort_t*)emb_src + (long)c * LATENT;
        for (int d = 0; d < LATENT; d++){ float v = bf2f(e[d]); s += v * v; }
      } else {
        const float* e = (const float*)emb_src + (long)c * LATENT;
        for (int d = 0; d < LATENT; d++){ float v = bf2f(f2bf(e[d])); s += v * v; }
      }
      enorm[c] = s;
    }
  }
}

// all 6 weight transposes in ONE launch. src[R][C] -> dst[C][R] bf16.
// grid 2816 x 256: seg tile counts 256,1024,128,128,1024,256.
__global__ void k_tcvt6(const void* s0, ushort_t* d0, const void* s1, ushort_t* d1,
                        const void* s2, ushort_t* d2, const void* s3, ushort_t* d3,
                        const void* s4, ushort_t* d4, const void* s5, ushort_t* d5,
                        const int* __restrict__ flagp){
  __shared__ ushort_t tile[32][33];
  int f = *flagp;
  int t = blockIdx.x;
  const void* src; ushort_t* dst; int R, C, lcx;
  if (t < 256)      { src=s0; dst=d0; R=256;  C=1024; lcx=5; }
  else if (t < 1280){ src=s1; dst=d1; R=1024; C=1024; lcx=5; t-=256;  }
  else if (t < 1408){ src=s2; dst=d2; R=1024; C=128;  lcx=2; t-=1280; }
  else if (t < 1536){ src=s3; dst=d3; R=128;  C=1024; lcx=5; t-=1408; }
  else if (t < 2560){ src=s4; dst=d4; R=1024; C=1024; lcx=5; t-=1536; }
  else              { src=s5; dst=d5; R=1024; C=256;  lcx=3; t-=2560; }
  int bx = t & ((C >> 5) - 1), by = t >> lcx;
  int tx = threadIdx.x & 31, ty = threadIdx.x >> 5;
  int c = bx * 32 + tx;
  #pragma unroll
  for (int ii = 0; ii < 4; ii++){
    int r = by * 32 + ty + ii * 8;
    long idx = (long)r * C + c;
    tile[ty + ii * 8][tx] = f ? ((const ushort_t*)src)[idx] : f2bf(((const float*)src)[idx]);
  }
  __syncthreads();
  #pragma unroll
  for (int ii = 0; ii < 4; ii++){
    int cc = bx * 32 + ty + ii * 8;
    dst[(long)cc * R + by * 32 + tx] = tile[tx][ty + ii * 8];
  }
}

// =====================================================================
// WIDE MFMA GEMM (N==1024): C = tanh(A[M,K] @ Bt[N,K]^T + b)
// 128x256 block tile, BK=64. Proven ~73us / 40% MfmaUtil on K=1024.
// True regs ~108 VGPR + 128 acc => 2 blocks/CU; cross-block TLP hides
// the per-tile drain. This is the m97-structure ceiling (~940 TF).
// =====================================================================
__global__ __launch_bounds__(256, 2)
void k_gemmw(const ushort_t* __restrict__ A, const ushort_t* __restrict__ Bt,
             const float* __restrict__ bias, int K,
             ushort_t* __restrict__ outb)
{
  const int N = 1024;
  __shared__ __align__(16) ushort_t As[128 * 64];   // 16 KB
  __shared__ __align__(16) ushort_t Bs[256 * 64];   // 32 KB
  const int tid = threadIdx.x;
  const int w = tid >> 6, lane = tid & 63;
  const int lane15 = lane & 15, quad = lane >> 4;
  const int wr = w >> 1, wc = w & 1;

  // ---- XCD-locality swizzle: 4 n-tiles (256 wide), 256 m-tiles ----
  const int f = blockIdx.x;
  const int j8 = f & 7, s = f >> 3;
  const int n_idx = s & 3;
  const int m_idx = ((s >> 2) << 3) | j8;
  const long m0 = (long)m_idx * 128;
  const int n0 = n_idx * 256;

  // staging lane decomposition: r = lane>>3 (8 rows/shot), c = lane&7
  const int lrow = lane >> 3;
  const int lk8  = (((lane & 7) ^ (lrow & 7)) * 8);   // XOR-swizzled k-chunk
  const int rx   = lane15 & 7;

  f32x4 acc[4][8];
  #pragma unroll
  for (int i = 0; i < 4; i++)
    #pragma unroll
    for (int j = 0; j < 8; j++) acc[i][j] = (f32x4){0.f, 0.f, 0.f, 0.f};

  const int nk = K >> 6;
  for (int kb = 0; kb < nk; kb++){
    const int k0 = kb << 6;
    __syncthreads();
    #pragma unroll
    for (int a = 0; a < 4; a++){
      int m = w * 32 + a * 8 + lrow;
      async16(A + ((m0 + m) * K + k0 + lk8), &As[(w * 32 + a * 8) * 64]);
    }
    #pragma unroll
    for (int b = 0; b < 8; b++){
      int n = w * 64 + b * 8 + lrow;
      async16(Bt + ((long)(n0 + n) * K + k0 + lk8), &Bs[(w * 64 + b * 8) * 64]);
    }
    __builtin_amdgcn_s_waitcnt(0);
    __syncthreads();

    #pragma unroll
    for (int h = 0; h < 2; h++){
      bf16x8 af[4], bf[8];
      #pragma unroll
      for (int i = 0; i < 4; i++){
        int rho = wr * 64 + i * 16 + lane15;
        af[i] = *(const bf16x8*)&As[rho * 64 + ((((h << 2) | quad) ^ rx) * 8)];
      }
      #pragma unroll
      for (int j = 0; j < 8; j++){
        int rho = wc * 128 + j * 16 + lane15;
        bf[j] = *(const bf16x8*)&Bs[rho * 64 + ((((h << 2) | quad) ^ rx) * 8)];
      }
      #pragma unroll
      for (int i = 0; i < 4; i++)
        #pragma unroll
        for (int j = 0; j < 8; j++)
          acc[i][j] = __builtin_amdgcn_mfma_f32_16x16x32_bf16(af[i], bf[j], acc[i][j], 0, 0, 0);
    }
  }

  #pragma unroll
  for (int i = 0; i < 4; i++){
    int row_l = wr * 64 + i * 16 + quad * 4;
    #pragma unroll
    for (int j = 0; j < 8; j++){
      int col = n0 + wc * 128 + j * 16 + lane15;
      float b = bias[col];
      #pragma unroll
      for (int r = 0; r < 4; r++){
        float v = fast_tanh(acc[i][j][r] + b);
        outb[(m0 + row_l + r) * N + col] = f2bf(v);
      }
    }
  }
}

// =====================================================================
// SLIM MFMA GEMM: 64xBN block tile, BK=64, 4 waves, wave = 32 x BN/2.
// MODE 0: tanh -> bf16 buffer outb (N-stride cols)          [L0 layers]
// MODE 2: recon: d_out only (flag dtype)                    [N=BN=256]
// =====================================================================
template<int MODE, int BN>
__global__ __launch_bounds__(256)
void k_gemm64(const ushort_t* __restrict__ A, const ushort_t* __restrict__ Bt,
              const float* __restrict__ bias, int N, int K,
              ushort_t* __restrict__ outb, float* __restrict__ outf,
              void* __restrict__ dout, long dout_off,
              const int* __restrict__ flagp)
{
  constexpr int NJ = BN / 32;                 // j-frags per wave: 8 (BN=256) / 4 (BN=128)
  __shared__ __align__(16) ushort_t As[64 * 64];    // 8 KB
  __shared__ __align__(16) ushort_t Bs[BN * 64];    // 32/16 KB
  const int tid = threadIdx.x;
  const int w = tid >> 6, lane = tid & 63;
  const int lane15 = lane & 15, quad = lane >> 4;
  const int wr = w >> 1, wc = w & 1;

  const int nx = N / BN;                      // 1 or 4
  const int lnx = __builtin_ctz(nx);
  const int f = blockIdx.x;
  const int j8 = f & 7, s = f >> 3;
  const int n_idx = s & (nx - 1);
  const int m_idx = ((s >> lnx) << 3) | j8;
  const long m0 = (long)m_idx * 64;
  const int n0 = n_idx * BN;

  const int lrow = lane >> 3;
  const int lk8  = (((lane & 7) ^ lrow) << 3);
  const int rx   = lane15 & 7;

  f32x4 acc[2][NJ];
  #pragma unroll
  for (int i = 0; i < 2; i++)
    #pragma unroll
    for (int j = 0; j < NJ; j++) acc[i][j] = (f32x4){0.f, 0.f, 0.f, 0.f};

  const int nk = K >> 6;
  for (int kb = 0; kb < nk; kb++){
    const int k0 = kb << 6;
    __syncthreads();
    #pragma unroll
    for (int a = 0; a < 2; a++){
      int m = w * 16 + a * 8 + lrow;
      async16(A + ((m0 + m) * K + k0 + lk8), &As[(w * 16 + a * 8) * 64]);
    }
    #pragma unroll
    for (int b = 0; b < NJ; b++){
      int n = w * (BN / 4) + b * 8 + lrow;
      async16(Bt + ((long)(n0 + n) * K + k0 + lk8), &Bs[(w * (BN / 4) + b * 8) * 64]);
    }
    __builtin_amdgcn_s_waitcnt(0);
    __syncthreads();

    #pragma unroll
    for (int h = 0; h < 2; h++){
      bf16x8 af[2], bf[NJ];
      #pragma unroll
      for (int i = 0; i < 2; i++){
        int rho = wr * 32 + i * 16 + lane15;
        af[i] = *(const bf16x8*)&As[rho * 64 + ((((h << 2) | quad) ^ rx) * 8)];
      }
      #pragma unroll
      for (int j = 0; j < NJ; j++){
        int rho = wc * (BN / 2) + j * 16 + lane15;
        bf[j] = *(const bf16x8*)&Bs[rho * 64 + ((((h << 2) | quad) ^ rx) * 8)];
      }
      #pragma unroll
      for (int i = 0; i < 2; i++)
        #pragma unroll
        for (int j = 0; j < NJ; j++)
          acc[i][j] = __builtin_amdgcn_mfma_f32_16x16x32_bf16(af[i], bf[j], acc[i][j], 0, 0, 0);
    }
  }

  int fl = 0;
  if (MODE != 0) fl = *flagp;
  #pragma unroll
  for (int i = 0; i < 2; i++){
    int row_l = wr * 32 + i * 16 + quad * 4;
    #pragma unroll
    for (int j = 0; j < NJ; j++){
      int col = n0 + wc * (BN / 2) + j * 16 + lane15;
      float b = bias[col];
      #pragma unroll
      for (int r = 0; r < 4; r++){
        float v = acc[i][j][r] + b;
        long row = m0 + row_l + r;
        if (MODE == 0){
          outb[row * N + col] = f2bf(fast_tanh(v));
        } else {
          long idx = row * N + col;
          if (fl) ((ushort_t*)dout)[dout_off + idx] = f2bf(v);
          else    ((float*)dout)[dout_off + idx] = v;
        }
      }
    }
  }
  (void)outf;
}

// =====================================================================
// FUSED z-GEMM + VQ: one kernel, grid 512 x 256. Each block computes its
// full 64x128 z row-block (K=1024, BK=64), writes z to d_out only, stashes
// f2bf(z) straight into the swizzled zt LDS layout (same bits the old
// zb16 path produced => bit-identical scores/argmax), keeps f32 z in the
// accumulator registers for the loss, then runs the proven VQ score loop
// (8 codebook tiles streamed through LDS) + argmax + gather + loss partial.
// Eliminates zf32/zb16 buffers (~50 MB HBM round trip) and one launch.
// LDS is phase-shared: GEMM As|Bs (24 KB) -> VQ zt|et (48 KB).
// =====================================================================
__global__ __launch_bounds__(256)
void k_zvq(const ushort_t* __restrict__ A, const ushort_t* __restrict__ Bt,
           const float* __restrict__ bias, const ushort_t* __restrict__ embb,
           const float* __restrict__ enorm,
           ushort_t* __restrict__ qb, void* __restrict__ dout,
           long z_off, long zq_off,
           float* __restrict__ loss_part, const int* __restrict__ flagp)
{
  __shared__ __align__(16) ushort_t lds[24576];   // 48 KB
  __shared__ float lv[64][4];
  __shared__ int   li[64][4];
  __shared__ int   bi[64];
  __shared__ float red[4];

  ushort_t* As = lds;              // [64*64]   gemm phase
  ushort_t* Bs = lds + 4096;       // [128*64]  gemm phase
  ushort_t* zt = lds;              // [64*128]  vq phase
  ushort_t* et = lds + 8192;       // [128*128] vq phase

  const int tid = threadIdx.x;
  const int w = tid >> 6, lane = tid & 63;
  const int lane15 = lane & 15, quad = lane >> 4;
  const int wr = w >> 1, wc = w & 1;

  const int f = blockIdx.x;
  const int j8 = f & 7, s = f >> 3;
  const int m_idx = (s << 3) | j8;
  const long m0 = (long)m_idx * 64;

  const int lrow = lane >> 3;
  const int lk8  = (((lane & 7) ^ lrow) << 3);
  const int rx   = lane15 & 7;

  // ---------------- phase 1: z = A[64x1024] @ Bt[128][1024]^T ----------------
  f32x4 acc[2][4];
  #pragma unroll
  for (int i = 0; i < 2; i++)
    #pragma unroll
    for (int j = 0; j < 4; j++) acc[i][j] = (f32x4){0.f, 0.f, 0.f, 0.f};

  for (int kb = 0; kb < 16; kb++){
    const int k0 = kb << 6;
    __syncthreads();
    #pragma unroll
    for (int a = 0; a < 2; a++){
      int m = w * 16 + a * 8 + lrow;
      async16(A + ((m0 + m) * 1024 + k0 + lk8), &As[(w * 16 + a * 8) * 64]);
    }
    #pragma unroll
    for (int b = 0; b < 4; b++){
      int n = w * 32 + b * 8 + lrow;
      async16(Bt + ((long)n * 1024 + k0 + lk8), &Bs[(w * 32 + b * 8) * 64]);
    }
    __builtin_amdgcn_s_waitcnt(0);
    __syncthreads();

    #pragma unroll
    for (int h = 0; h < 2; h++){
      bf16x8 af[2], bf[4];
      #pragma unroll
      for (int i = 0; i < 2; i++){
        int rho = wr * 32 + i * 16 + lane15;
        af[i] = *(const bf16x8*)&As[rho * 64 + ((((h << 2) | quad) ^ rx) * 8)];
      }
      #pragma unroll
      for (int j = 0; j < 4; j++){
        int rho = wc * 64 + j * 16 + lane15;
        bf[j] = *(const bf16x8*)&Bs[rho * 64 + ((((h << 2) | quad) ^ rx) * 8)];
      }
      #pragma unroll
      for (int i = 0; i < 2; i++)
        #pragma unroll
        for (int j = 0; j < 4; j++)
          acc[i][j] = __builtin_amdgcn_mfma_f32_16x16x32_bf16(af[i], bf[j], acc[i][j], 0, 0, 0);
    }
  }

  const int fl = *flagp;
  // z = acc + bias (kept in acc, f32); write z to d_out
  #pragma unroll
  for (int i = 0; i < 2; i++){
    int row_l = wr * 32 + i * 16 + quad * 4;
    #pragma unroll
    for (int j = 0; j < 4; j++){
      int col = wc * 64 + j * 16 + lane15;
      float b = bias[col];
      #pragma unroll
      for (int r = 0; r < 4; r++){
        float v = acc[i][j][r] + b;
        acc[i][j][r] = v;
        long idx = (m0 + row_l + r) * 128 + col;
        if (fl) ((ushort_t*)dout)[z_off + idx] = f2bf(v);
        else    ((float*)dout)[z_off + idx] = v;
      }
    }
  }

  __syncthreads();   // all ds_reads of As/Bs retired; LDS repurposed below

  // deposit f2bf(z) into zt with the k-chunk XOR swizzle:
  // physical chunk slot p of row rho holds global chunk p ^ (rho & 15)
  #pragma unroll
  for (int i = 0; i < 2; i++){
    #pragma unroll
    for (int j = 0; j < 4; j++){
      int col = wc * 64 + j * 16 + lane15;
      int g = col >> 3, cw = col & 7;
      #pragma unroll
      for (int r = 0; r < 4; r++){
        int row_l = wr * 32 + i * 16 + quad * 4 + r;
        zt[row_l * 128 + ((g ^ (row_l & 15)) << 3) + cw] = f2bf(acc[i][j][r]);
      }
    }
  }
  // stage emb tile 0 (et region is disjoint from zt writes)
  const int srow = lane >> 4, schk = lane & 15;
  #pragma unroll
  for (int s8 = 0; s8 < 8; s8++){
    int r = w * 32 + s8 * 4 + srow;
    async16(embb + (long)r * 128 + ((schk ^ (r & 15)) * 8), &et[(w * 32 + s8 * 4) * 128]);
  }
  __builtin_amdgcn_s_waitcnt(0);
  __syncthreads();

  // ---------------- phase 2: VQ scores + running argmax ----------------
  float bestv[16];
  int   bestc[16];
  #pragma unroll
  for (int u = 0; u < 16; u++){ bestv[u] = -1e30f; bestc[u] = 0; }

  for (int t = 0; t < 8; t++){
    f32x4 sacc[4][2];
    #pragma unroll
    for (int i = 0; i < 4; i++){
      sacc[i][0] = (f32x4){0.f, 0.f, 0.f, 0.f};
      sacc[i][1] = (f32x4){0.f, 0.f, 0.f, 0.f};
    }
    #pragma unroll
    for (int ks = 0; ks < 4; ks++){
      bf16x8 af[4], bf[2];
      #pragma unroll
      for (int i = 0; i < 4; i++){
        int rho = i * 16 + lane15;
        af[i] = *(const bf16x8*)&zt[rho * 128 + ((((ks << 2) | quad) ^ (rho & 15)) * 8)];
      }
      #pragma unroll
      for (int j = 0; j < 2; j++){
        int rho = w * 32 + j * 16 + lane15;
        bf[j] = *(const bf16x8*)&et[rho * 128 + ((((ks << 2) | quad) ^ (rho & 15)) * 8)];
      }
      #pragma unroll
      for (int i = 0; i < 4; i++)
        #pragma unroll
        for (int j = 0; j < 2; j++)
          sacc[i][j] = __builtin_amdgcn_mfma_f32_16x16x32_bf16(af[i], bf[j], sacc[i][j], 0, 0, 0);
    }
    // fold into running best (codes ascending: j then t => ties keep lowest)
    #pragma unroll
    for (int i = 0; i < 4; i++)
      #pragma unroll
      for (int r = 0; r < 4; r++)
        #pragma unroll
        for (int j = 0; j < 2; j++){
          int code = t * 128 + w * 32 + j * 16 + lane15;
          float v = sacc[i][j][r] - 0.5f * enorm[code];
          int u = i * 4 + r;
          if (v > bestv[u]){ bestv[u] = v; bestc[u] = code; }
        }
    if (t < 7){
      __syncthreads();
      #pragma unroll
      for (int s8 = 0; s8 < 8; s8++){
        int r = w * 32 + s8 * 4 + srow;
        async16(embb + ((long)(t + 1) * 128 + r) * 128 + ((schk ^ (r & 15)) * 8),
                &et[(w * 32 + s8 * 4) * 128]);
      }
      __builtin_amdgcn_s_waitcnt(0);
      __syncthreads();
    }
  }

  // per-wave argmax (16-lane groups hold 16 distinct codes per (i,r))
  #pragma unroll
  for (int i = 0; i < 4; i++)
    #pragma unroll
    for (int r = 0; r < 4; r++){
      float bv = bestv[i * 4 + r]; int bc = bestc[i * 4 + r];
      #pragma unroll
      for (int off = 1; off < 16; off <<= 1){
        float ov = __shfl_xor(bv, off, 64);
        int   oc = __shfl_xor(bc, off, 64);
        if (ov > bv || (ov == bv && oc < bc)){ bv = ov; bc = oc; }
      }
      if (lane15 == 0){
        int row_l = i * 16 + quad * 4 + r;
        lv[row_l][w] = bv; li[row_l][w] = bc;
      }
    }
  __syncthreads();
  // cross-wave combine (w ascending = code ascending; tie keeps lowest)
  if (tid < 64){
    float bv = lv[tid][0]; int bc = li[tid][0];
    #pragma unroll
    for (int ww = 1; ww < 4; ww++){
      float ov = lv[tid][ww]; int oc = li[tid][ww];
      if (ov > bv || (ov == bv && oc < bc)){ bv = ov; bc = oc; }
    }
    bi[tid] = bc;
  }
  __syncthreads();

  // ---------------- finalize: gather, zq/qb writes, loss partial ----------------
  float p = 0.f;
  #pragma unroll
  for (int i = 0; i < 2; i++){
    #pragma unroll
    for (int j = 0; j < 4; j++){
      int col = wc * 64 + j * 16 + lane15;
      #pragma unroll
      for (int r = 0; r < 4; r++){
        int row_l = wr * 32 + i * 16 + quad * 4 + r;
        int code = bi[row_l];
        ushort_t qbits = embb[(long)code * LATENT + col];
        float qv = bf2f(qbits);
        long idx = (m0 + row_l) * LATENT + col;
        qb[idx] = qbits;
        if (fl) ((ushort_t*)dout)[zq_off + idx] = qbits;
        else    ((float*)dout)[zq_off + idx] = qv;
        float diff = acc[i][j][r] - qv;
        p += diff * diff;
      }
    }
  }
  #pragma unroll
  for (int off = 32; off; off >>= 1) p += __shfl_down(p, off, 64);
  if ((tid & 63) == 0) red[tid >> 6] = p;
  __syncthreads();
  if (tid == 0) loss_part[blockIdx.x] = red[0] + red[1] + red[2] + red[3];
}

__global__ __launch_bounds__(256)
void k_lossfin(const float* __restrict__ loss_part, void* __restrict__ dout,
               long off, const int* __restrict__ flagp){
  __shared__ float red[4];
  float s = 0.f;
  for (int i = threadIdx.x; i < 512; i += 256) s += loss_part[i];
  #pragma unroll
  for (int o = 32; o; o >>= 1) s += __shfl_down(s, o, 64);
  if ((threadIdx.x & 63) == 0) red[threadIdx.x >> 6] = s;
  __syncthreads();
  if (threadIdx.x == 0){
    float v = 1.25f * (red[0] + red[1] + red[2] + red[3]) / (float)((long)BB * LATENT);
    if (*flagp) ((ushort_t*)dout)[off] = f2bf(v);
    else        ((float*)dout)[off] = v;
  }
}

// =====================================================================
extern "C" void kernel_launch(void* const* d_in, const int* in_sizes, int n_in,
                              void* d_out, int out_size, void* d_ws, size_t ws_size,
                              hipStream_t stream)
{
  (void)in_sizes; (void)n_in; (void)out_size; (void)ws_size;
  const void* action = d_in[1];
  const void* eW0 = d_in[2];  const void* eb0 = d_in[3];
  const void* eW1 = d_in[4];  const void* eb1 = d_in[5];
  const void* eW2 = d_in[6];  const void* eb2 = d_in[7];
  const void* emb = d_in[8];
  const void* dW0 = d_in[9];  const void* db0 = d_in[10];
  const void* dW1 = d_in[11]; const void* db1 = d_in[12];
  const void* dW2 = d_in[13]; const void* db2 = d_in[14];

  char* ws = (char*)d_ws;
  size_t off = 0;
  auto alloc = [&](size_t bytes)->char*{
    char* p = ws + off; off += bytes; off = (off + 255) & ~((size_t)255); return p;
  };
  int*      flag     = (int*)  alloc(4);
  float*    biasf    = (float*)alloc(6 * 1024 * 4);
  float*    enorm    = (float*)alloc(KCODES * 4);
  ushort_t* eW0t = (ushort_t*)alloc((size_t)HID * INDIM * 2);
  ushort_t* eW1t = (ushort_t*)alloc((size_t)HID * HID * 2);
  ushort_t* eW2t = (ushort_t*)alloc((size_t)LATENT * HID * 2);
  ushort_t* embb = (ushort_t*)alloc((size_t)KCODES * LATENT * 2);
  ushort_t* dW0t = (ushort_t*)alloc((size_t)HID * LATENT * 2);
  ushort_t* dW1t = (ushort_t*)alloc((size_t)HID * HID * 2);
  ushort_t* dW2t = (ushort_t*)alloc((size_t)INDIM * HID * 2);
  ushort_t* act0 = (ushort_t*)alloc((size_t)BB * INDIM * 2);
  ushort_t* hA   = (ushort_t*)alloc((size_t)BB * HID * 2);
  ushort_t* hB   = (ushort_t*)alloc((size_t)BB * HID * 2);
  ushort_t* qb16 = (ushort_t*)alloc((size_t)BB * LATENT * 2);
  float*    loss_part = (float*)alloc((size_t)512 * 4);

  const long z_off  = (long)BB * INDIM;
  const long zq_off = z_off + (long)BB * LATENT;
  const long l_off  = zq_off + (long)BB * LATENT;

  // ---- prep (3 launches) ----
  k_sniff<<<1, 64, 0, stream>>>((const ushort_t*)action, flag);
  {
    const int A8 = BB * INDIM / 8, E8 = KCODES * LATENT / 8;
    int total = A8 + E8 + 6144 + KCODES;
    k_prep<<<(total + 255) / 256, 256, 0, stream>>>(action, act0, emb, embb,
        eb0, eb1, eb2, db0, db1, db2, biasf, enorm, flag);
  }
  k_tcvt6<<<2816, 256, 0, stream>>>(eW0, eW0t, eW1, eW1t, eW2, eW2t,
                                    dW0, dW0t, dW1, dW1t, dW2, dW2t, flag);

  // ---- encoder ----
  k_gemm64<0, 256><<<2048, 256, 0, stream>>>(act0, eW0t, biasf + 0, 1024, INDIM,
      hA, nullptr, nullptr, 0, flag);                                          // K=256
  k_gemmw<<<1024, 256, 0, stream>>>(hA, eW1t, biasf + 1024, HID, hB);          // K=1024

  // ---- fused z-GEMM + VQ ----
  k_zvq<<<512, 256, 0, stream>>>(hB, eW2t, biasf + 2048, embb, enorm,
      qb16, d_out, z_off, zq_off, loss_part, flag);

  // ---- decoder ----
  k_gemm64<0, 256><<<2048, 256, 0, stream>>>(qb16, dW0t, biasf + 3072, 1024, LATENT,
      hA, nullptr, nullptr, 0, flag);                                          // K=128
  k_gemmw<<<1024, 256, 0, stream>>>(hA, dW1t, biasf + 4096, HID, hB);          // K=1024
  k_gemm64<2, 256><<<512, 256, 0, stream>>>(hB, dW2t, biasf + 5120, 256, HID,
      nullptr, nullptr, d_out, 0, flag);                                       // recon

  k_lossfin<<<1, 256, 0, stream>>>(loss_part, d_out, l_off, flag);
}

// Round 5
// 364.325 us; speedup vs baseline: 1.4773x; 1.1294x over previous
//
#include <hip/hip_runtime.h>
#include <stdint.h>
#include <math.h>

#define DEVI __device__ __forceinline__
typedef unsigned short ushort_t;
typedef __attribute__((ext_vector_type(8))) __bf16 bf16x8;
typedef __attribute__((ext_vector_type(4))) float f32x4;

// ---------- scalar bf16 helpers (RNE, matches HW/harness encoding) ----------
DEVI float bf2f(ushort_t b){ union{uint32_t u; float f;} c; c.u = ((uint32_t)b) << 16; return c.f; }
DEVI ushort_t f2bf(float f){ union{float f; uint32_t u;} c; c.f = f; uint32_t u = c.u;
                             u += 0x7fffu + ((u >> 16) & 1u); return (ushort_t)(u >> 16); }

// fast tanh: 1 - 2/(exp2(2*log2e*x)+1). ~5 VALU ops, saturates correctly.
DEVI float fast_tanh(float x){
  float t = __builtin_amdgcn_exp2f(x * 2.8853900817779268f);
  return 1.0f - 2.0f * __builtin_amdgcn_rcpf(t + 1.0f);
}

// ---------- async global->LDS (16B per lane, dest = wave-uniform base + lane*16) ----------
DEVI void async16(const ushort_t* g, ushort_t* l){
  __builtin_amdgcn_global_load_lds((const __attribute__((address_space(1))) void*)g,
                                   (__attribute__((address_space(3))) void*)l, 16, 0, 0);
}

// ---------- problem constants ----------
#define BB 32768
#define INDIM 256
#define LATENT 128
#define HID 1024
#define KCODES 1024

// =====================================================================
// dtype sniffer: flag = 1 -> buffers are bf16 ; flag = 0 -> fp32
// =====================================================================
__global__ void k_sniff(const ushort_t* __restrict__ act, int* flag){
  if (threadIdx.x == 0){
    int bad = 0;
    for (int i = 0; i < 256; i++){
      float v = bf2f(act[i]);
      float a = fabsf(v);
      if (!(a <= 16.0f) || (a > 0.0f && a < 9.5e-7f)) bad++;
    }
    flag[0] = (bad >= 8) ? 0 : 1;
  }
}

// merged prep: action->bf16, emb->bf16, 6 biases->fp32, enorm, ONE launch.
// segments: A8=BB*INDIM/8, E8=KCODES*LATENT/8, 6144 bias slots, 1024 enorm.
__global__ void k_prep(const void* __restrict__ act_src, ushort_t* __restrict__ act_dst,
                       const void* __restrict__ emb_src, ushort_t* __restrict__ emb_dst,
                       const void* b0, const void* b1, const void* b2,
                       const void* b3, const void* b4, const void* b5,
                       float* __restrict__ biasf, float* __restrict__ enorm,
                       const int* __restrict__ flagp){
  const int f = *flagp;
  const int A8 = BB * INDIM / 8;
  const int E8 = KCODES * LATENT / 8;
  int i = blockIdx.x * blockDim.x + threadIdx.x;
  if (i < A8 + E8){
    const void* src; ushort_t* dst; int k;
    if (i < A8){ src = act_src; dst = act_dst; k = i; }
    else       { src = emb_src; dst = emb_dst; k = i - A8; }
    if (f){
      ((uint4*)dst)[k] = ((const uint4*)src)[k];
    } else {
      const float* s = (const float*)src + (size_t)k * 8;
      ushort_t o[8];
      #pragma unroll
      for (int j = 0; j < 8; j++) o[j] = f2bf(s[j]);
      ((uint4*)dst)[k] = *(const uint4*)o;
    }
  } else {
    int k = i - A8 - E8;
    if (k < 6144){
      int seg = k >> 10, off = k & 1023;
      const void* sp; int n;
      switch (seg){
        case 0: sp = b0; n = 1024; break;
        case 1: sp = b1; n = 1024; break;
        case 2: sp = b2; n = 128;  break;
        case 3: sp = b3; n = 1024; break;
        case 4: sp = b4; n = 1024; break;
        default: sp = b5; n = 256; break;
      }
      if (off < n)
        biasf[seg * 1024 + off] = f ? bf2f(((const ushort_t*)sp)[off]) : ((const float*)sp)[off];
    } else if (k < 6144 + KCODES){
      // ||e_c||^2 from the bf16-rounded codebook (bit-identical to old k_enorm)
      int c = k - 6144;
      float s = 0.f;
      if (f){
        const ushort_t* e = (const ushort_t*)emb_src + (long)c * LATENT;
        for (int d = 0; d < LATENT; d++){ float v = bf2f(e[d]); s += v * v; }
      } else {
        const float* e = (const float*)emb_src + (long)c * LATENT;
        for (int d = 0; d < LATENT; d++){ float v = bf2f(f2bf(e[d])); s += v * v; }
      }
      enorm[c] = s;
    }
  }
}

// all 6 weight transposes in ONE launch. src[R][C] -> dst[C][R] bf16.
// grid 2816 x 256: seg tile counts 256,1024,128,128,1024,256.
__global__ void k_tcvt6(const void* s0, ushort_t* d0, const void* s1, ushort_t* d1,
                        const void* s2, ushort_t* d2, const void* s3, ushort_t* d3,
                        const void* s4, ushort_t* d4, const void* s5, ushort_t* d5,
                        const int* __restrict__ flagp){
  __shared__ ushort_t tile[32][33];
  int f = *flagp;
  int t = blockIdx.x;
  const void* src; ushort_t* dst; int R, C, lcx;
  if (t < 256)      { src=s0; dst=d0; R=256;  C=1024; lcx=5; }
  else if (t < 1280){ src=s1; dst=d1; R=1024; C=1024; lcx=5; t-=256;  }
  else if (t < 1408){ src=s2; dst=d2; R=1024; C=128;  lcx=2; t-=1280; }
  else if (t < 1536){ src=s3; dst=d3; R=128;  C=1024; lcx=5; t-=1408; }
  else if (t < 2560){ src=s4; dst=d4; R=1024; C=1024; lcx=5; t-=1536; }
  else              { src=s5; dst=d5; R=1024; C=256;  lcx=3; t-=2560; }
  int bx = t & ((C >> 5) - 1), by = t >> lcx;
  int tx = threadIdx.x & 31, ty = threadIdx.x >> 5;
  int c = bx * 32 + tx;
  #pragma unroll
  for (int ii = 0; ii < 4; ii++){
    int r = by * 32 + ty + ii * 8;
    long idx = (long)r * C + c;
    tile[ty + ii * 8][tx] = f ? ((const ushort_t*)src)[idx] : f2bf(((const float*)src)[idx]);
  }
  __syncthreads();
  #pragma unroll
  for (int ii = 0; ii < 4; ii++){
    int cc = bx * 32 + ty + ii * 8;
    dst[(long)cc * R + by * 32 + tx] = tile[tx][ty + ii * 8];
  }
}

// =====================================================================
// WIDE MFMA GEMM (N==1024): C = tanh(A[M,K] @ Bt[N,K]^T + b)
// 128x256 block tile, BK=64. Proven ~73us / 40% MfmaUtil on K=1024.
// Grid = (M/128)*4; bijective XCD swizzle for any grid = 8*g.
// Output element depends only on A-row/B-col bits (fixed kb->h->MFMA
// fold order) => same kernel on codebook rows is bit-identical.
// =====================================================================
__global__ __launch_bounds__(256, 2)
void k_gemmw(const ushort_t* __restrict__ A, const ushort_t* __restrict__ Bt,
             const float* __restrict__ bias, int K,
             ushort_t* __restrict__ outb)
{
  const int N = 1024;
  __shared__ __align__(16) ushort_t As[128 * 64];   // 16 KB
  __shared__ __align__(16) ushort_t Bs[256 * 64];   // 32 KB
  const int tid = threadIdx.x;
  const int w = tid >> 6, lane = tid & 63;
  const int lane15 = lane & 15, quad = lane >> 4;
  const int wr = w >> 1, wc = w & 1;

  const int f = blockIdx.x;
  const int j8 = f & 7, s = f >> 3;
  const int n_idx = s & 3;
  const int m_idx = ((s >> 2) << 3) | j8;
  const long m0 = (long)m_idx * 128;
  const int n0 = n_idx * 256;

  const int lrow = lane >> 3;
  const int lk8  = (((lane & 7) ^ (lrow & 7)) * 8);   // XOR-swizzled k-chunk
  const int rx   = lane15 & 7;

  f32x4 acc[4][8];
  #pragma unroll
  for (int i = 0; i < 4; i++)
    #pragma unroll
    for (int j = 0; j < 8; j++) acc[i][j] = (f32x4){0.f, 0.f, 0.f, 0.f};

  const int nk = K >> 6;
  for (int kb = 0; kb < nk; kb++){
    const int k0 = kb << 6;
    __syncthreads();
    #pragma unroll
    for (int a = 0; a < 4; a++){
      int m = w * 32 + a * 8 + lrow;
      async16(A + ((m0 + m) * K + k0 + lk8), &As[(w * 32 + a * 8) * 64]);
    }
    #pragma unroll
    for (int b = 0; b < 8; b++){
      int n = w * 64 + b * 8 + lrow;
      async16(Bt + ((long)(n0 + n) * K + k0 + lk8), &Bs[(w * 64 + b * 8) * 64]);
    }
    __builtin_amdgcn_s_waitcnt(0);
    __syncthreads();

    #pragma unroll
    for (int h = 0; h < 2; h++){
      bf16x8 af[4], bf[8];
      #pragma unroll
      for (int i = 0; i < 4; i++){
        int rho = wr * 64 + i * 16 + lane15;
        af[i] = *(const bf16x8*)&As[rho * 64 + ((((h << 2) | quad) ^ rx) * 8)];
      }
      #pragma unroll
      for (int j = 0; j < 8; j++){
        int rho = wc * 128 + j * 16 + lane15;
        bf[j] = *(const bf16x8*)&Bs[rho * 64 + ((((h << 2) | quad) ^ rx) * 8)];
      }
      #pragma unroll
      for (int i = 0; i < 4; i++)
        #pragma unroll
        for (int j = 0; j < 8; j++)
          acc[i][j] = __builtin_amdgcn_mfma_f32_16x16x32_bf16(af[i], bf[j], acc[i][j], 0, 0, 0);
    }
  }

  #pragma unroll
  for (int i = 0; i < 4; i++){
    int row_l = wr * 64 + i * 16 + quad * 4;
    #pragma unroll
    for (int j = 0; j < 8; j++){
      int col = n0 + wc * 128 + j * 16 + lane15;
      float b = bias[col];
      #pragma unroll
      for (int r = 0; r < 4; r++){
        float v = fast_tanh(acc[i][j][r] + b);
        outb[(m0 + row_l + r) * N + col] = f2bf(v);
      }
    }
  }
}

// =====================================================================
// SLIM MFMA GEMM: 64xBN block tile, BK=64, 4 waves, wave = 32 x BN/2.
// MODE 0: tanh -> bf16 buffer outb (N-stride cols)          [L0 / tA]
// MODE 2: recon: d_out only (flag dtype)                    [unused now]
// MODE 3: f32 -> outf (N-stride)                            [recon table]
// =====================================================================
template<int MODE, int BN>
__global__ __launch_bounds__(256)
void k_gemm64(const ushort_t* __restrict__ A, const ushort_t* __restrict__ Bt,
              const float* __restrict__ bias, int N, int K,
              ushort_t* __restrict__ outb, float* __restrict__ outf,
              void* __restrict__ dout, long dout_off,
              const int* __restrict__ flagp)
{
  constexpr int NJ = BN / 32;                 // j-frags per wave: 8 (BN=256) / 4 (BN=128)
  __shared__ __align__(16) ushort_t As[64 * 64];    // 8 KB
  __shared__ __align__(16) ushort_t Bs[BN * 64];    // 32/16 KB
  const int tid = threadIdx.x;
  const int w = tid >> 6, lane = tid & 63;
  const int lane15 = lane & 15, quad = lane >> 4;
  const int wr = w >> 1, wc = w & 1;

  const int nx = N / BN;                      // 1 or 4
  const int lnx = __builtin_ctz(nx);
  const int f = blockIdx.x;
  const int j8 = f & 7, s = f >> 3;
  const int n_idx = s & (nx - 1);
  const int m_idx = ((s >> lnx) << 3) | j8;
  const long m0 = (long)m_idx * 64;
  const int n0 = n_idx * BN;

  const int lrow = lane >> 3;
  const int lk8  = (((lane & 7) ^ lrow) << 3);
  const int rx   = lane15 & 7;

  f32x4 acc[2][NJ];
  #pragma unroll
  for (int i = 0; i < 2; i++)
    #pragma unroll
    for (int j = 0; j < NJ; j++) acc[i][j] = (f32x4){0.f, 0.f, 0.f, 0.f};

  const int nk = K >> 6;
  for (int kb = 0; kb < nk; kb++){
    const int k0 = kb << 6;
    __syncthreads();
    #pragma unroll
    for (int a = 0; a < 2; a++){
      int m = w * 16 + a * 8 + lrow;
      async16(A + ((m0 + m) * K + k0 + lk8), &As[(w * 16 + a * 8) * 64]);
    }
    #pragma unroll
    for (int b = 0; b < NJ; b++){
      int n = w * (BN / 4) + b * 8 + lrow;
      async16(Bt + ((long)(n0 + n) * K + k0 + lk8), &Bs[(w * (BN / 4) + b * 8) * 64]);
    }
    __builtin_amdgcn_s_waitcnt(0);
    __syncthreads();

    #pragma unroll
    for (int h = 0; h < 2; h++){
      bf16x8 af[2], bf[NJ];
      #pragma unroll
      for (int i = 0; i < 2; i++){
        int rho = wr * 32 + i * 16 + lane15;
        af[i] = *(const bf16x8*)&As[rho * 64 + ((((h << 2) | quad) ^ rx) * 8)];
      }
      #pragma unroll
      for (int j = 0; j < NJ; j++){
        int rho = wc * (BN / 2) + j * 16 + lane15;
        bf[j] = *(const bf16x8*)&Bs[rho * 64 + ((((h << 2) | quad) ^ rx) * 8)];
      }
      #pragma unroll
      for (int i = 0; i < 2; i++)
        #pragma unroll
        for (int j = 0; j < NJ; j++)
          acc[i][j] = __builtin_amdgcn_mfma_f32_16x16x32_bf16(af[i], bf[j], acc[i][j], 0, 0, 0);
    }
  }

  int fl = 0;
  if (MODE == 2) fl = *flagp;
  #pragma unroll
  for (int i = 0; i < 2; i++){
    int row_l = wr * 32 + i * 16 + quad * 4;
    #pragma unroll
    for (int j = 0; j < NJ; j++){
      int col = n0 + wc * (BN / 2) + j * 16 + lane15;
      float b = bias[col];
      #pragma unroll
      for (int r = 0; r < 4; r++){
        float v = acc[i][j][r] + b;
        long row = m0 + row_l + r;
        if (MODE == 0){
          outb[row * N + col] = f2bf(fast_tanh(v));
        } else if (MODE == 3){
          outf[row * N + col] = v;
        } else {
          long idx = row * N + col;
          if (fl) ((ushort_t*)dout)[dout_off + idx] = f2bf(v);
          else    ((float*)dout)[dout_off + idx] = v;
        }
      }
    }
  }
}

// =====================================================================
// FUSED z-GEMM + VQ: grid 512 x 256. Computes 64x128 z row-block
// (K=1024), writes z to d_out, stashes f2bf(z) into swizzled zt LDS,
// streams 8 codebook tiles, running argmax, writes zq + codes + loss.
// =====================================================================
__global__ __launch_bounds__(256)
void k_zvq(const ushort_t* __restrict__ A, const ushort_t* __restrict__ Bt,
           const float* __restrict__ bias, const ushort_t* __restrict__ embb,
           const float* __restrict__ enorm,
           int* __restrict__ codes, void* __restrict__ dout,
           long z_off, long zq_off,
           float* __restrict__ loss_part, const int* __restrict__ flagp)
{
  __shared__ __align__(16) ushort_t lds[24576];   // 48 KB
  __shared__ float lv[64][4];
  __shared__ int   li[64][4];
  __shared__ int   bi[64];
  __shared__ float red[4];

  ushort_t* As = lds;              // [64*64]   gemm phase
  ushort_t* Bs = lds + 4096;       // [128*64]  gemm phase
  ushort_t* zt = lds;              // [64*128]  vq phase
  ushort_t* et = lds + 8192;       // [128*128] vq phase

  const int tid = threadIdx.x;
  const int w = tid >> 6, lane = tid & 63;
  const int lane15 = lane & 15, quad = lane >> 4;
  const int wr = w >> 1, wc = w & 1;

  const int f = blockIdx.x;
  const int j8 = f & 7, s = f >> 3;
  const int m_idx = (s << 3) | j8;
  const long m0 = (long)m_idx * 64;

  const int lrow = lane >> 3;
  const int lk8  = (((lane & 7) ^ lrow) << 3);
  const int rx   = lane15 & 7;

  // ---------------- phase 1: z = A[64x1024] @ Bt[128][1024]^T ----------------
  f32x4 acc[2][4];
  #pragma unroll
  for (int i = 0; i < 2; i++)
    #pragma unroll
    for (int j = 0; j < 4; j++) acc[i][j] = (f32x4){0.f, 0.f, 0.f, 0.f};

  for (int kb = 0; kb < 16; kb++){
    const int k0 = kb << 6;
    __syncthreads();
    #pragma unroll
    for (int a = 0; a < 2; a++){
      int m = w * 16 + a * 8 + lrow;
      async16(A + ((m0 + m) * 1024 + k0 + lk8), &As[(w * 16 + a * 8) * 64]);
    }
    #pragma unroll
    for (int b = 0; b < 4; b++){
      int n = w * 32 + b * 8 + lrow;
      async16(Bt + ((long)n * 1024 + k0 + lk8), &Bs[(w * 32 + b * 8) * 64]);
    }
    __builtin_amdgcn_s_waitcnt(0);
    __syncthreads();

    #pragma unroll
    for (int h = 0; h < 2; h++){
      bf16x8 af[2], bf[4];
      #pragma unroll
      for (int i = 0; i < 2; i++){
        int rho = wr * 32 + i * 16 + lane15;
        af[i] = *(const bf16x8*)&As[rho * 64 + ((((h << 2) | quad) ^ rx) * 8)];
      }
      #pragma unroll
      for (int j = 0; j < 4; j++){
        int rho = wc * 64 + j * 16 + lane15;
        bf[j] = *(const bf16x8*)&Bs[rho * 64 + ((((h << 2) | quad) ^ rx) * 8)];
      }
      #pragma unroll
      for (int i = 0; i < 2; i++)
        #pragma unroll
        for (int j = 0; j < 4; j++)
          acc[i][j] = __builtin_amdgcn_mfma_f32_16x16x32_bf16(af[i], bf[j], acc[i][j], 0, 0, 0);
    }
  }

  const int fl = *flagp;
  // z = acc + bias (kept in acc, f32); write z to d_out
  #pragma unroll
  for (int i = 0; i < 2; i++){
    int row_l = wr * 32 + i * 16 + quad * 4;
    #pragma unroll
    for (int j = 0; j < 4; j++){
      int col = wc * 64 + j * 16 + lane15;
      float b = bias[col];
      #pragma unroll
      for (int r = 0; r < 4; r++){
        float v = acc[i][j][r] + b;
        acc[i][j][r] = v;
        long idx = (m0 + row_l + r) * 128 + col;
        if (fl) ((ushort_t*)dout)[z_off + idx] = f2bf(v);
        else    ((float*)dout)[z_off + idx] = v;
      }
    }
  }

  __syncthreads();   // all ds_reads of As/Bs retired; LDS repurposed below

  // deposit f2bf(z) into zt with the k-chunk XOR swizzle
  #pragma unroll
  for (int i = 0; i < 2; i++){
    #pragma unroll
    for (int j = 0; j < 4; j++){
      int col = wc * 64 + j * 16 + lane15;
      int g = col >> 3, cw = col & 7;
      #pragma unroll
      for (int r = 0; r < 4; r++){
        int row_l = wr * 32 + i * 16 + quad * 4 + r;
        zt[row_l * 128 + ((g ^ (row_l & 15)) << 3) + cw] = f2bf(acc[i][j][r]);
      }
    }
  }
  // stage emb tile 0 (et region is disjoint from zt writes)
  const int srow = lane >> 4, schk = lane & 15;
  #pragma unroll
  for (int s8 = 0; s8 < 8; s8++){
    int r = w * 32 + s8 * 4 + srow;
    async16(embb + (long)r * 128 + ((schk ^ (r & 15)) * 8), &et[(w * 32 + s8 * 4) * 128]);
  }
  __builtin_amdgcn_s_waitcnt(0);
  __syncthreads();

  // ---------------- phase 2: VQ scores + running argmax ----------------
  float bestv[16];
  int   bestc[16];
  #pragma unroll
  for (int u = 0; u < 16; u++){ bestv[u] = -1e30f; bestc[u] = 0; }

  for (int t = 0; t < 8; t++){
    f32x4 sacc[4][2];
    #pragma unroll
    for (int i = 0; i < 4; i++){
      sacc[i][0] = (f32x4){0.f, 0.f, 0.f, 0.f};
      sacc[i][1] = (f32x4){0.f, 0.f, 0.f, 0.f};
    }
    #pragma unroll
    for (int ks = 0; ks < 4; ks++){
      bf16x8 af[4], bf[2];
      #pragma unroll
      for (int i = 0; i < 4; i++){
        int rho = i * 16 + lane15;
        af[i] = *(const bf16x8*)&zt[rho * 128 + ((((ks << 2) | quad) ^ (rho & 15)) * 8)];
      }
      #pragma unroll
      for (int j = 0; j < 2; j++){
        int rho = w * 32 + j * 16 + lane15;
        bf[j] = *(const bf16x8*)&et[rho * 128 + ((((ks << 2) | quad) ^ (rho & 15)) * 8)];
      }
      #pragma unroll
      for (int i = 0; i < 4; i++)
        #pragma unroll
        for (int j = 0; j < 2; j++)
          sacc[i][j] = __builtin_amdgcn_mfma_f32_16x16x32_bf16(af[i], bf[j], sacc[i][j], 0, 0, 0);
    }
    #pragma unroll
    for (int i = 0; i < 4; i++)
      #pragma unroll
      for (int r = 0; r < 4; r++)
        #pragma unroll
        for (int j = 0; j < 2; j++){
          int code = t * 128 + w * 32 + j * 16 + lane15;
          float v = sacc[i][j][r] - 0.5f * enorm[code];
          int u = i * 4 + r;
          if (v > bestv[u]){ bestv[u] = v; bestc[u] = code; }
        }
    if (t < 7){
      __syncthreads();
      #pragma unroll
      for (int s8 = 0; s8 < 8; s8++){
        int r = w * 32 + s8 * 4 + srow;
        async16(embb + ((long)(t + 1) * 128 + r) * 128 + ((schk ^ (r & 15)) * 8),
                &et[(w * 32 + s8 * 4) * 128]);
      }
      __builtin_amdgcn_s_waitcnt(0);
      __syncthreads();
    }
  }

  // per-wave argmax (16-lane groups hold 16 distinct codes per (i,r))
  #pragma unroll
  for (int i = 0; i < 4; i++)
    #pragma unroll
    for (int r = 0; r < 4; r++){
      float bv = bestv[i * 4 + r]; int bc = bestc[i * 4 + r];
      #pragma unroll
      for (int off = 1; off < 16; off <<= 1){
        float ov = __shfl_xor(bv, off, 64);
        int   oc = __shfl_xor(bc, off, 64);
        if (ov > bv || (ov == bv && oc < bc)){ bv = ov; bc = oc; }
      }
      if (lane15 == 0){
        int row_l = i * 16 + quad * 4 + r;
        lv[row_l][w] = bv; li[row_l][w] = bc;
      }
    }
  __syncthreads();
  if (tid < 64){
    float bv = lv[tid][0]; int bc = li[tid][0];
    #pragma unroll
    for (int ww = 1; ww < 4; ww++){
      float ov = lv[tid][ww]; int oc = li[tid][ww];
      if (ov > bv || (ov == bv && oc < bc)){ bv = ov; bc = oc; }
    }
    bi[tid] = bc;
    codes[m0 + tid] = bc;
  }
  __syncthreads();

  // ---------------- finalize: gather, zq writes, loss partial ----------------
  float p = 0.f;
  #pragma unroll
  for (int i = 0; i < 2; i++){
    #pragma unroll
    for (int j = 0; j < 4; j++){
      int col = wc * 64 + j * 16 + lane15;
      #pragma unroll
      for (int r = 0; r < 4; r++){
        int row_l = wr * 32 + i * 16 + quad * 4 + r;
        int code = bi[row_l];
        ushort_t qbits = embb[(long)code * LATENT + col];
        float qv = bf2f(qbits);
        long idx = (m0 + row_l) * LATENT + col;
        if (fl) ((ushort_t*)dout)[zq_off + idx] = qbits;
        else    ((float*)dout)[zq_off + idx] = qv;
        float diff = acc[i][j][r] - qv;
        p += diff * diff;
      }
    }
  }
  #pragma unroll
  for (int off = 32; off; off >>= 1) p += __shfl_down(p, off, 64);
  if ((tid & 63) == 0) red[tid >> 6] = p;
  __syncthreads();
  if (tid == 0) loss_part[blockIdx.x] = red[0] + red[1] + red[2] + red[3];
}

// =====================================================================
// recon gather: out[row] = rt[codes[row]] (flag-dtype). grid 4096 x 256.
// 8 rows/block, 32 lanes/row, 8 cols/lane.
// =====================================================================
__global__ __launch_bounds__(256)
void k_rgather(const float* __restrict__ rt, const int* __restrict__ codes,
               void* __restrict__ dout, const int* __restrict__ flagp){
  const int fl = *flagp;
  int row = blockIdx.x * 8 + (threadIdx.x >> 5);
  int c8 = (threadIdx.x & 31) * 8;
  int code = codes[row];
  const float* src = rt + (long)code * 256 + c8;
  float v[8];
  #pragma unroll
  for (int j = 0; j < 8; j++) v[j] = src[j];
  long base = (long)row * 256 + c8;
  if (fl){
    ushort_t o[8];
    #pragma unroll
    for (int j = 0; j < 8; j++) o[j] = f2bf(v[j]);
    *(uint4*)((ushort_t*)dout + base) = *(const uint4*)o;
  } else {
    float* d = (float*)dout + base;
    *(float4*)d = *(const float4*)v;
    *(float4*)(d + 4) = *(const float4*)(v + 4);
  }
}

__global__ __launch_bounds__(256)
void k_lossfin(const float* __restrict__ loss_part, void* __restrict__ dout,
               long off, const int* __restrict__ flagp){
  __shared__ float red[4];
  float s = 0.f;
  for (int i = threadIdx.x; i < 512; i += 256) s += loss_part[i];
  #pragma unroll
  for (int o = 32; o; o >>= 1) s += __shfl_down(s, o, 64);
  if ((threadIdx.x & 63) == 0) red[threadIdx.x >> 6] = s;
  __syncthreads();
  if (threadIdx.x == 0){
    float v = 1.25f * (red[0] + red[1] + red[2] + red[3]) / (float)((long)BB * LATENT);
    if (*flagp) ((ushort_t*)dout)[off] = f2bf(v);
    else        ((float*)dout)[off] = v;
  }
}

// =====================================================================
extern "C" void kernel_launch(void* const* d_in, const int* in_sizes, int n_in,
                              void* d_out, int out_size, void* d_ws, size_t ws_size,
                              hipStream_t stream)
{
  (void)in_sizes; (void)n_in; (void)out_size; (void)ws_size;
  const void* action = d_in[1];
  const void* eW0 = d_in[2];  const void* eb0 = d_in[3];
  const void* eW1 = d_in[4];  const void* eb1 = d_in[5];
  const void* eW2 = d_in[6];  const void* eb2 = d_in[7];
  const void* emb = d_in[8];
  const void* dW0 = d_in[9];  const void* db0 = d_in[10];
  const void* dW1 = d_in[11]; const void* db1 = d_in[12];
  const void* dW2 = d_in[13]; const void* db2 = d_in[14];

  char* ws = (char*)d_ws;
  size_t off = 0;
  auto alloc = [&](size_t bytes)->char*{
    char* p = ws + off; off += bytes; off = (off + 255) & ~((size_t)255); return p;
  };
  int*      flag     = (int*)  alloc(4);
  float*    biasf    = (float*)alloc(6 * 1024 * 4);
  float*    enorm    = (float*)alloc(KCODES * 4);
  ushort_t* eW0t = (ushort_t*)alloc((size_t)HID * INDIM * 2);
  ushort_t* eW1t = (ushort_t*)alloc((size_t)HID * HID * 2);
  ushort_t* eW2t = (ushort_t*)alloc((size_t)LATENT * HID * 2);
  ushort_t* embb = (ushort_t*)alloc((size_t)KCODES * LATENT * 2);
  ushort_t* dW0t = (ushort_t*)alloc((size_t)HID * LATENT * 2);
  ushort_t* dW1t = (ushort_t*)alloc((size_t)HID * HID * 2);
  ushort_t* dW2t = (ushort_t*)alloc((size_t)INDIM * HID * 2);
  ushort_t* act0 = (ushort_t*)alloc((size_t)BB * INDIM * 2);
  ushort_t* hA   = (ushort_t*)alloc((size_t)BB * HID * 2);
  ushort_t* hB   = (ushort_t*)alloc((size_t)BB * HID * 2);
  ushort_t* tA   = (ushort_t*)alloc((size_t)KCODES * HID * 2);   // decoder table L0
  ushort_t* tB   = (ushort_t*)alloc((size_t)KCODES * HID * 2);   // decoder table L1
  float*    rt   = (float*)   alloc((size_t)KCODES * INDIM * 4); // recon table (f32)
  int*      codes = (int*)    alloc((size_t)BB * 4);
  float*    loss_part = (float*)alloc((size_t)512 * 4);

  const long z_off  = (long)BB * INDIM;
  const long zq_off = z_off + (long)BB * LATENT;
  const long l_off  = zq_off + (long)BB * LATENT;

  // ---- prep ----
  k_sniff<<<1, 64, 0, stream>>>((const ushort_t*)action, flag);
  {
    const int A8 = BB * INDIM / 8, E8 = KCODES * LATENT / 8;
    int total = A8 + E8 + 6144 + KCODES;
    k_prep<<<(total + 255) / 256, 256, 0, stream>>>(action, act0, emb, embb,
        eb0, eb1, eb2, db0, db1, db2, biasf, enorm, flag);
  }
  k_tcvt6<<<2816, 256, 0, stream>>>(eW0, eW0t, eW1, eW1t, eW2, eW2t,
                                    dW0, dW0t, dW1, dW1t, dW2, dW2t, flag);

  // ---- decoder tables over the 1024 codebook rows (bit-identical kernels) ----
  k_gemm64<0, 256><<<64, 256, 0, stream>>>(embb, dW0t, biasf + 3072, 1024, LATENT,
      tA, nullptr, nullptr, 0, flag);                                          // tanh(emb@dW0+b)
  k_gemmw<<<32, 256, 0, stream>>>(tA, dW1t, biasf + 4096, HID, tB);            // tanh(tA@dW1+b)
  k_gemm64<3, 256><<<16, 256, 0, stream>>>(tB, dW2t, biasf + 5120, 256, HID,
      nullptr, rt, nullptr, 0, flag);                                          // recon table f32

  // ---- encoder ----
  k_gemm64<0, 256><<<2048, 256, 0, stream>>>(act0, eW0t, biasf + 0, 1024, INDIM,
      hA, nullptr, nullptr, 0, flag);                                          // K=256
  k_gemmw<<<1024, 256, 0, stream>>>(hA, eW1t, biasf + 1024, HID, hB);          // K=1024

  // ---- fused z-GEMM + VQ (emits codes) ----
  k_zvq<<<512, 256, 0, stream>>>(hB, eW2t, biasf + 2048, embb, enorm,
      codes, d_out, z_off, zq_off, loss_part, flag);

  // ---- decoder = table gather ----
  k_rgather<<<BB / 8, 256, 0, stream>>>(rt, codes, d_out, flag);

  k_lossfin<<<1, 256, 0, stream>>>(loss_part, d_out, l_off, flag);
}

// Round 6
// 340.307 us; speedup vs baseline: 1.5816x; 1.0706x over previous
//
#include <hip/hip_runtime.h>
#include <stdint.h>
#include <math.h>

#define DEVI __device__ __forceinline__
typedef unsigned short ushort_t;
typedef __attribute__((ext_vector_type(8))) __bf16 bf16x8;
typedef __attribute__((ext_vector_type(4))) float f32x4;

// ---------- scalar bf16 helpers (RNE, matches HW/harness encoding) ----------
DEVI float bf2f(ushort_t b){ union{uint32_t u; float f;} c; c.u = ((uint32_t)b) << 16; return c.f; }
DEVI ushort_t f2bf(float f){ union{float f; uint32_t u;} c; c.f = f; uint32_t u = c.u;
                             u += 0x7fffu + ((u >> 16) & 1u); return (ushort_t)(u >> 16); }

// fast tanh: 1 - 2/(exp2(2*log2e*x)+1). ~5 VALU ops, saturates correctly.
DEVI float fast_tanh(float x){
  float t = __builtin_amdgcn_exp2f(x * 2.8853900817779268f);
  return 1.0f - 2.0f * __builtin_amdgcn_rcpf(t + 1.0f);
}

// ---------- async global->LDS (16B per lane, dest = wave-uniform base + lane*16) ----------
DEVI void async16(const ushort_t* g, ushort_t* l){
  __builtin_amdgcn_global_load_lds((const __attribute__((address_space(1))) void*)g,
                                   (__attribute__((address_space(3))) void*)l, 16, 0, 0);
}

// ---------- problem constants ----------
#define BB 32768
#define INDIM 256
#define LATENT 128
#define HID 1024
#define KCODES 1024

// =====================================================================
// dtype sniffer: flag = 1 -> buffers are bf16 ; flag = 0 -> fp32
// =====================================================================
__global__ void k_sniff(const ushort_t* __restrict__ act, int* flag){
  if (threadIdx.x == 0){
    int bad = 0;
    for (int i = 0; i < 256; i++){
      float v = bf2f(act[i]);
      float a = fabsf(v);
      if (!(a <= 16.0f) || (a > 0.0f && a < 9.5e-7f)) bad++;
    }
    flag[0] = (bad >= 8) ? 0 : 1;
  }
}

// merged prep: action->bf16, emb->bf16, 6 biases->fp32, enorm, ONE launch.
__global__ void k_prep(const void* __restrict__ act_src, ushort_t* __restrict__ act_dst,
                       const void* __restrict__ emb_src, ushort_t* __restrict__ emb_dst,
                       const void* b0, const void* b1, const void* b2,
                       const void* b3, const void* b4, const void* b5,
                       float* __restrict__ biasf, float* __restrict__ enorm,
                       const int* __restrict__ flagp){
  const int f = *flagp;
  const int A8 = BB * INDIM / 8;
  const int E8 = KCODES * LATENT / 8;
  int i = blockIdx.x * blockDim.x + threadIdx.x;
  if (i < A8 + E8){
    const void* src; ushort_t* dst; int k;
    if (i < A8){ src = act_src; dst = act_dst; k = i; }
    else       { src = emb_src; dst = emb_dst; k = i - A8; }
    if (f){
      ((uint4*)dst)[k] = ((const uint4*)src)[k];
    } else {
      const float* s = (const float*)src + (size_t)k * 8;
      ushort_t o[8];
      #pragma unroll
      for (int j = 0; j < 8; j++) o[j] = f2bf(s[j]);
      ((uint4*)dst)[k] = *(const uint4*)o;
    }
  } else {
    int k = i - A8 - E8;
    if (k < 6144){
      int seg = k >> 10, off = k & 1023;
      const void* sp; int n;
      switch (seg){
        case 0: sp = b0; n = 1024; break;
        case 1: sp = b1; n = 1024; break;
        case 2: sp = b2; n = 128;  break;
        case 3: sp = b3; n = 1024; break;
        case 4: sp = b4; n = 1024; break;
        default: sp = b5; n = 256; break;
      }
      if (off < n)
        biasf[seg * 1024 + off] = f ? bf2f(((const ushort_t*)sp)[off]) : ((const float*)sp)[off];
    } else if (k < 6144 + KCODES){
      int c = k - 6144;
      float s = 0.f;
      if (f){
        const ushort_t* e = (const ushort_t*)emb_src + (long)c * LATENT;
        for (int d = 0; d < LATENT; d++){ float v = bf2f(e[d]); s += v * v; }
      } else {
        const float* e = (const float*)emb_src + (long)c * LATENT;
        for (int d = 0; d < LATENT; d++){ float v = bf2f(f2bf(e[d])); s += v * v; }
      }
      enorm[c] = s;
    }
  }
}

// all 6 weight transposes in ONE launch. src[R][C] -> dst[C][R] bf16.
__global__ void k_tcvt6(const void* s0, ushort_t* d0, const void* s1, ushort_t* d1,
                        const void* s2, ushort_t* d2, const void* s3, ushort_t* d3,
                        const void* s4, ushort_t* d4, const void* s5, ushort_t* d5,
                        const int* __restrict__ flagp){
  __shared__ ushort_t tile[32][33];
  int f = *flagp;
  int t = blockIdx.x;
  const void* src; ushort_t* dst; int R, C, lcx;
  if (t < 256)      { src=s0; dst=d0; R=256;  C=1024; lcx=5; }
  else if (t < 1280){ src=s1; dst=d1; R=1024; C=1024; lcx=5; t-=256;  }
  else if (t < 1408){ src=s2; dst=d2; R=1024; C=128;  lcx=2; t-=1280; }
  else if (t < 1536){ src=s3; dst=d3; R=128;  C=1024; lcx=5; t-=1408; }
  else if (t < 2560){ src=s4; dst=d4; R=1024; C=1024; lcx=5; t-=1536; }
  else              { src=s5; dst=d5; R=1024; C=256;  lcx=3; t-=2560; }
  int bx = t & ((C >> 5) - 1), by = t >> lcx;
  int tx = threadIdx.x & 31, ty = threadIdx.x >> 5;
  int c = bx * 32 + tx;
  #pragma unroll
  for (int ii = 0; ii < 4; ii++){
    int r = by * 32 + ty + ii * 8;
    long idx = (long)r * C + c;
    tile[ty + ii * 8][tx] = f ? ((const ushort_t*)src)[idx] : f2bf(((const float*)src)[idx]);
  }
  __syncthreads();
  #pragma unroll
  for (int ii = 0; ii < 4; ii++){
    int cc = bx * 32 + ty + ii * 8;
    dst[(long)cc * R + by * 32 + tx] = tile[tx][ty + ii * 8];
  }
}

// =====================================================================
// WIDE MFMA GEMM (N==1024): C = tanh(A[M,K] @ Bt[N,K]^T + b)
// 128x256 block tile, BK=64. Proven ~73us / 40% MfmaUtil on K=1024.
// TWO-SEGMENT launch: blocks [0,nblk1) use (A,Bt,bias,K,outb);
// blocks [nblk1, grid) use the *2 params — lets tiny table GEMMs ride
// along inside big launches instead of running on an empty GPU.
// Per-element fold order (kb asc -> h -> MFMA) is M/grid-independent
// => outputs bit-identical to any segment split.
// =====================================================================
__global__ __launch_bounds__(256, 2)
void k_gemmw(const ushort_t* __restrict__ A, const ushort_t* __restrict__ Bt,
             const float* __restrict__ bias, int K,
             ushort_t* __restrict__ outb,
             int nblk1,
             const ushort_t* __restrict__ A2, const ushort_t* __restrict__ Bt2,
             const float* __restrict__ bias2, int K2,
             ushort_t* __restrict__ outb2)
{
  const int N = 1024;
  __shared__ __align__(16) ushort_t As[128 * 64];   // 16 KB
  __shared__ __align__(16) ushort_t Bs[256 * 64];   // 32 KB
  const int tid = threadIdx.x;
  const int w = tid >> 6, lane = tid & 63;
  const int lane15 = lane & 15, quad = lane >> 4;
  const int wr = w >> 1, wc = w & 1;

  int f = blockIdx.x;
  if (f >= nblk1){ A = A2; Bt = Bt2; bias = bias2; K = K2; outb = outb2; f -= nblk1; }

  const int j8 = f & 7, s = f >> 3;
  const int n_idx = s & 3;
  const int m_idx = ((s >> 2) << 3) | j8;
  const long m0 = (long)m_idx * 128;
  const int n0 = n_idx * 256;

  const int lrow = lane >> 3;
  const int lk8  = (((lane & 7) ^ (lrow & 7)) * 8);   // XOR-swizzled k-chunk
  const int rx   = lane15 & 7;

  f32x4 acc[4][8];
  #pragma unroll
  for (int i = 0; i < 4; i++)
    #pragma unroll
    for (int j = 0; j < 8; j++) acc[i][j] = (f32x4){0.f, 0.f, 0.f, 0.f};

  const int nk = K >> 6;
  for (int kb = 0; kb < nk; kb++){
    const int k0 = kb << 6;
    __syncthreads();
    #pragma unroll
    for (int a = 0; a < 4; a++){
      int m = w * 32 + a * 8 + lrow;
      async16(A + ((m0 + m) * K + k0 + lk8), &As[(w * 32 + a * 8) * 64]);
    }
    #pragma unroll
    for (int b = 0; b < 8; b++){
      int n = w * 64 + b * 8 + lrow;
      async16(Bt + ((long)(n0 + n) * K + k0 + lk8), &Bs[(w * 64 + b * 8) * 64]);
    }
    __builtin_amdgcn_s_waitcnt(0);
    __syncthreads();

    #pragma unroll
    for (int h = 0; h < 2; h++){
      bf16x8 af[4], bf[8];
      #pragma unroll
      for (int i = 0; i < 4; i++){
        int rho = wr * 64 + i * 16 + lane15;
        af[i] = *(const bf16x8*)&As[rho * 64 + ((((h << 2) | quad) ^ rx) * 8)];
      }
      #pragma unroll
      for (int j = 0; j < 8; j++){
        int rho = wc * 128 + j * 16 + lane15;
        bf[j] = *(const bf16x8*)&Bs[rho * 64 + ((((h << 2) | quad) ^ rx) * 8)];
      }
      #pragma unroll
      for (int i = 0; i < 4; i++)
        #pragma unroll
        for (int j = 0; j < 8; j++)
          acc[i][j] = __builtin_amdgcn_mfma_f32_16x16x32_bf16(af[i], bf[j], acc[i][j], 0, 0, 0);
    }
  }

  #pragma unroll
  for (int i = 0; i < 4; i++){
    int row_l = wr * 64 + i * 16 + quad * 4;
    #pragma unroll
    for (int j = 0; j < 8; j++){
      int col = n0 + wc * 128 + j * 16 + lane15;
      float b = bias[col];
      #pragma unroll
      for (int r = 0; r < 4; r++){
        float v = fast_tanh(acc[i][j][r] + b);
        outb[(m0 + row_l + r) * N + col] = f2bf(v);
      }
    }
  }
}

// =====================================================================
// FUSED z-GEMM + VQ (blocks [0,512)) + recon-table GEMM (blocks [512,528)).
// Main body: computes 64x128 z row-block (K=1024), writes z to d_out,
// stashes f2bf(z) into swizzled zt LDS, streams 8 codebook tiles,
// running argmax, writes zq + codes + loss partial.
// Table body: rt[1024][256] = tB@dW2t^T + b in f32 (64x256 tile, BK=64),
// riding along so the decoder table never runs on an empty GPU.
// =====================================================================
__global__ __launch_bounds__(256)
void k_zvq(const ushort_t* __restrict__ A, const ushort_t* __restrict__ Bt,
           const float* __restrict__ bias, const ushort_t* __restrict__ embb,
           const float* __restrict__ enorm,
           int* __restrict__ codes, void* __restrict__ dout,
           long z_off, long zq_off,
           float* __restrict__ loss_part, const int* __restrict__ flagp,
           const ushort_t* __restrict__ tB, const ushort_t* __restrict__ dW2t,
           const float* __restrict__ bias3, float* __restrict__ rt)
{
  __shared__ __align__(16) ushort_t lds[24576];   // 48 KB
  __shared__ float lv[64][4];
  __shared__ int   li[64][4];
  __shared__ int   bi[64];
  __shared__ float red[4];

  const int tid = threadIdx.x;
  const int w = tid >> 6, lane = tid & 63;
  const int lane15 = lane & 15, quad = lane >> 4;
  const int wr = w >> 1, wc = w & 1;
  const int lrow = lane >> 3;
  const int rx   = lane15 & 7;

  // ---------------- table segment: rt = tB @ dW2t^T + b (f32) ----------------
  if (blockIdx.x >= 512){
    ushort_t* As = lds;              // [64*64]   8 KB
    ushort_t* Bs = lds + 4096;       // [256*64] 32 KB
    const long m0 = (long)(blockIdx.x - 512) * 64;
    const int lk8 = (((lane & 7) ^ lrow) << 3);

    f32x4 tacc[2][8];
    #pragma unroll
    for (int i = 0; i < 2; i++)
      #pragma unroll
      for (int j = 0; j < 8; j++) tacc[i][j] = (f32x4){0.f, 0.f, 0.f, 0.f};

    for (int kb = 0; kb < 16; kb++){
      const int k0 = kb << 6;
      __syncthreads();
      #pragma unroll
      for (int a = 0; a < 2; a++){
        int m = w * 16 + a * 8 + lrow;
        async16(tB + ((m0 + m) * 1024 + k0 + lk8), &As[(w * 16 + a * 8) * 64]);
      }
      #pragma unroll
      for (int b = 0; b < 8; b++){
        int n = w * 64 + b * 8 + lrow;
        async16(dW2t + ((long)n * 1024 + k0 + lk8), &Bs[(w * 64 + b * 8) * 64]);
      }
      __builtin_amdgcn_s_waitcnt(0);
      __syncthreads();

      #pragma unroll
      for (int h = 0; h < 2; h++){
        bf16x8 af[2], bf[8];
        #pragma unroll
        for (int i = 0; i < 2; i++){
          int rho = wr * 32 + i * 16 + lane15;
          af[i] = *(const bf16x8*)&As[rho * 64 + ((((h << 2) | quad) ^ rx) * 8)];
        }
        #pragma unroll
        for (int j = 0; j < 8; j++){
          int rho = wc * 128 + j * 16 + lane15;
          bf[j] = *(const bf16x8*)&Bs[rho * 64 + ((((h << 2) | quad) ^ rx) * 8)];
        }
        #pragma unroll
        for (int i = 0; i < 2; i++)
          #pragma unroll
          for (int j = 0; j < 8; j++)
            tacc[i][j] = __builtin_amdgcn_mfma_f32_16x16x32_bf16(af[i], bf[j], tacc[i][j], 0, 0, 0);
      }
    }
    #pragma unroll
    for (int i = 0; i < 2; i++){
      int row_l = wr * 32 + i * 16 + quad * 4;
      #pragma unroll
      for (int j = 0; j < 8; j++){
        int col = wc * 128 + j * 16 + lane15;
        float b = bias3[col];
        #pragma unroll
        for (int r = 0; r < 4; r++)
          rt[(m0 + row_l + r) * 256 + col] = tacc[i][j][r] + b;
      }
    }
    return;
  }

  ushort_t* As = lds;              // [64*64]   gemm phase
  ushort_t* Bs = lds + 4096;       // [128*64]  gemm phase
  ushort_t* zt = lds;              // [64*128]  vq phase
  ushort_t* et = lds + 8192;       // [128*128] vq phase

  const int f = blockIdx.x;
  const int j8 = f & 7, s = f >> 3;
  const int m_idx = (s << 3) | j8;
  const long m0 = (long)m_idx * 64;
  const int lk8  = (((lane & 7) ^ lrow) << 3);

  // ---------------- phase 1: z = A[64x1024] @ Bt[128][1024]^T ----------------
  f32x4 acc[2][4];
  #pragma unroll
  for (int i = 0; i < 2; i++)
    #pragma unroll
    for (int j = 0; j < 4; j++) acc[i][j] = (f32x4){0.f, 0.f, 0.f, 0.f};

  for (int kb = 0; kb < 16; kb++){
    const int k0 = kb << 6;
    __syncthreads();
    #pragma unroll
    for (int a = 0; a < 2; a++){
      int m = w * 16 + a * 8 + lrow;
      async16(A + ((m0 + m) * 1024 + k0 + lk8), &As[(w * 16 + a * 8) * 64]);
    }
    #pragma unroll
    for (int b = 0; b < 4; b++){
      int n = w * 32 + b * 8 + lrow;
      async16(Bt + ((long)n * 1024 + k0 + lk8), &Bs[(w * 32 + b * 8) * 64]);
    }
    __builtin_amdgcn_s_waitcnt(0);
    __syncthreads();

    #pragma unroll
    for (int h = 0; h < 2; h++){
      bf16x8 af[2], bf[4];
      #pragma unroll
      for (int i = 0; i < 2; i++){
        int rho = wr * 32 + i * 16 + lane15;
        af[i] = *(const bf16x8*)&As[rho * 64 + ((((h << 2) | quad) ^ rx) * 8)];
      }
      #pragma unroll
      for (int j = 0; j < 4; j++){
        int rho = wc * 64 + j * 16 + lane15;
        bf[j] = *(const bf16x8*)&Bs[rho * 64 + ((((h << 2) | quad) ^ rx) * 8)];
      }
      #pragma unroll
      for (int i = 0; i < 2; i++)
        #pragma unroll
        for (int j = 0; j < 4; j++)
          acc[i][j] = __builtin_amdgcn_mfma_f32_16x16x32_bf16(af[i], bf[j], acc[i][j], 0, 0, 0);
    }
  }

  const int fl = *flagp;
  // z = acc + bias (kept in acc, f32); write z to d_out
  #pragma unroll
  for (int i = 0; i < 2; i++){
    int row_l = wr * 32 + i * 16 + quad * 4;
    #pragma unroll
    for (int j = 0; j < 4; j++){
      int col = wc * 64 + j * 16 + lane15;
      float b = bias[col];
      #pragma unroll
      for (int r = 0; r < 4; r++){
        float v = acc[i][j][r] + b;
        acc[i][j][r] = v;
        long idx = (m0 + row_l + r) * 128 + col;
        if (fl) ((ushort_t*)dout)[z_off + idx] = f2bf(v);
        else    ((float*)dout)[z_off + idx] = v;
      }
    }
  }

  __syncthreads();   // all ds_reads of As/Bs retired; LDS repurposed below

  // deposit f2bf(z) into zt with the k-chunk XOR swizzle
  #pragma unroll
  for (int i = 0; i < 2; i++){
    #pragma unroll
    for (int j = 0; j < 4; j++){
      int col = wc * 64 + j * 16 + lane15;
      int g = col >> 3, cw = col & 7;
      #pragma unroll
      for (int r = 0; r < 4; r++){
        int row_l = wr * 32 + i * 16 + quad * 4 + r;
        zt[row_l * 128 + ((g ^ (row_l & 15)) << 3) + cw] = f2bf(acc[i][j][r]);
      }
    }
  }
  // stage emb tile 0 (et region is disjoint from zt writes)
  const int srow = lane >> 4, schk = lane & 15;
  #pragma unroll
  for (int s8 = 0; s8 < 8; s8++){
    int r = w * 32 + s8 * 4 + srow;
    async16(embb + (long)r * 128 + ((schk ^ (r & 15)) * 8), &et[(w * 32 + s8 * 4) * 128]);
  }
  __builtin_amdgcn_s_waitcnt(0);
  __syncthreads();

  // ---------------- phase 2: VQ scores + running argmax ----------------
  float bestv[16];
  int   bestc[16];
  #pragma unroll
  for (int u = 0; u < 16; u++){ bestv[u] = -1e30f; bestc[u] = 0; }

  for (int t = 0; t < 8; t++){
    f32x4 sacc[4][2];
    #pragma unroll
    for (int i = 0; i < 4; i++){
      sacc[i][0] = (f32x4){0.f, 0.f, 0.f, 0.f};
      sacc[i][1] = (f32x4){0.f, 0.f, 0.f, 0.f};
    }
    #pragma unroll
    for (int ks = 0; ks < 4; ks++){
      bf16x8 af[4], bf[2];
      #pragma unroll
      for (int i = 0; i < 4; i++){
        int rho = i * 16 + lane15;
        af[i] = *(const bf16x8*)&zt[rho * 128 + ((((ks << 2) | quad) ^ (rho & 15)) * 8)];
      }
      #pragma unroll
      for (int j = 0; j < 2; j++){
        int rho = w * 32 + j * 16 + lane15;
        bf[j] = *(const bf16x8*)&et[rho * 128 + ((((ks << 2) | quad) ^ (rho & 15)) * 8)];
      }
      #pragma unroll
      for (int i = 0; i < 4; i++)
        #pragma unroll
        for (int j = 0; j < 2; j++)
          sacc[i][j] = __builtin_amdgcn_mfma_f32_16x16x32_bf16(af[i], bf[j], sacc[i][j], 0, 0, 0);
    }
    #pragma unroll
    for (int i = 0; i < 4; i++)
      #pragma unroll
      for (int r = 0; r < 4; r++)
        #pragma unroll
        for (int j = 0; j < 2; j++){
          int code = t * 128 + w * 32 + j * 16 + lane15;
          float v = sacc[i][j][r] - 0.5f * enorm[code];
          int u = i * 4 + r;
          if (v > bestv[u]){ bestv[u] = v; bestc[u] = code; }
        }
    if (t < 7){
      __syncthreads();
      #pragma unroll
      for (int s8 = 0; s8 < 8; s8++){
        int r = w * 32 + s8 * 4 + srow;
        async16(embb + ((long)(t + 1) * 128 + r) * 128 + ((schk ^ (r & 15)) * 8),
                &et[(w * 32 + s8 * 4) * 128]);
      }
      __builtin_amdgcn_s_waitcnt(0);
      __syncthreads();
    }
  }

  // per-wave argmax (16-lane groups hold 16 distinct codes per (i,r))
  #pragma unroll
  for (int i = 0; i < 4; i++)
    #pragma unroll
    for (int r = 0; r < 4; r++){
      float bv = bestv[i * 4 + r]; int bc = bestc[i * 4 + r];
      #pragma unroll
      for (int off = 1; off < 16; off <<= 1){
        float ov = __shfl_xor(bv, off, 64);
        int   oc = __shfl_xor(bc, off, 64);
        if (ov > bv || (ov == bv && oc < bc)){ bv = ov; bc = oc; }
      }
      if (lane15 == 0){
        int row_l = i * 16 + quad * 4 + r;
        lv[row_l][w] = bv; li[row_l][w] = bc;
      }
    }
  __syncthreads();
  if (tid < 64){
    float bv = lv[tid][0]; int bc = li[tid][0];
    #pragma unroll
    for (int ww = 1; ww < 4; ww++){
      float ov = lv[tid][ww]; int oc = li[tid][ww];
      if (ov > bv || (ov == bv && oc < bc)){ bv = ov; bc = oc; }
    }
    bi[tid] = bc;
    codes[m0 + tid] = bc;
  }
  __syncthreads();

  // ---------------- finalize: gather, zq writes, loss partial ----------------
  float p = 0.f;
  #pragma unroll
  for (int i = 0; i < 2; i++){
    #pragma unroll
    for (int j = 0; j < 4; j++){
      int col = wc * 64 + j * 16 + lane15;
      #pragma unroll
      for (int r = 0; r < 4; r++){
        int row_l = wr * 32 + i * 16 + quad * 4 + r;
        int code = bi[row_l];
        ushort_t qbits = embb[(long)code * LATENT + col];
        float qv = bf2f(qbits);
        long idx = (m0 + row_l) * LATENT + col;
        if (fl) ((ushort_t*)dout)[zq_off + idx] = qbits;
        else    ((float*)dout)[zq_off + idx] = qv;
        float diff = acc[i][j][r] - qv;
        p += diff * diff;
      }
    }
  }
  #pragma unroll
  for (int off = 32; off; off >>= 1) p += __shfl_down(p, off, 64);
  if ((tid & 63) == 0) red[tid >> 6] = p;
  __syncthreads();
  if (tid == 0) loss_part[blockIdx.x] = red[0] + red[1] + red[2] + red[3];
}

// =====================================================================
// recon gather: out[row] = rt[codes[row]] (flag-dtype). grid 4096 x 256.
// =====================================================================
__global__ __launch_bounds__(256)
void k_rgather(const float* __restrict__ rt, const int* __restrict__ codes,
               void* __restrict__ dout, const int* __restrict__ flagp){
  const int fl = *flagp;
  int row = blockIdx.x * 8 + (threadIdx.x >> 5);
  int c8 = (threadIdx.x & 31) * 8;
  int code = codes[row];
  const float* src = rt + (long)code * 256 + c8;
  float v[8];
  #pragma unroll
  for (int j = 0; j < 8; j++) v[j] = src[j];
  long base = (long)row * 256 + c8;
  if (fl){
    ushort_t o[8];
    #pragma unroll
    for (int j = 0; j < 8; j++) o[j] = f2bf(v[j]);
    *(uint4*)((ushort_t*)dout + base) = *(const uint4*)o;
  } else {
    float* d = (float*)dout + base;
    *(float4*)d = *(const float4*)v;
    *(float4*)(d + 4) = *(const float4*)(v + 4);
  }
}

__global__ __launch_bounds__(256)
void k_lossfin(const float* __restrict__ loss_part, void* __restrict__ dout,
               long off, const int* __restrict__ flagp){
  __shared__ float red[4];
  float s = 0.f;
  for (int i = threadIdx.x; i < 512; i += 256) s += loss_part[i];
  #pragma unroll
  for (int o = 32; o; o >>= 1) s += __shfl_down(s, o, 64);
  if ((threadIdx.x & 63) == 0) red[threadIdx.x >> 6] = s;
  __syncthreads();
  if (threadIdx.x == 0){
    float v = 1.25f * (red[0] + red[1] + red[2] + red[3]) / (float)((long)BB * LATENT);
    if (*flagp) ((ushort_t*)dout)[off] = f2bf(v);
    else        ((float*)dout)[off] = v;
  }
}

// =====================================================================
extern "C" void kernel_launch(void* const* d_in, const int* in_sizes, int n_in,
                              void* d_out, int out_size, void* d_ws, size_t ws_size,
                              hipStream_t stream)
{
  (void)in_sizes; (void)n_in; (void)out_size; (void)ws_size;
  const void* action = d_in[1];
  const void* eW0 = d_in[2];  const void* eb0 = d_in[3];
  const void* eW1 = d_in[4];  const void* eb1 = d_in[5];
  const void* eW2 = d_in[6];  const void* eb2 = d_in[7];
  const void* emb = d_in[8];
  const void* dW0 = d_in[9];  const void* db0 = d_in[10];
  const void* dW1 = d_in[11]; const void* db1 = d_in[12];
  const void* dW2 = d_in[13]; const void* db2 = d_in[14];

  char* ws = (char*)d_ws;
  size_t off = 0;
  auto alloc = [&](size_t bytes)->char*{
    char* p = ws + off; off += bytes; off = (off + 255) & ~((size_t)255); return p;
  };
  int*      flag     = (int*)  alloc(4);
  float*    biasf    = (float*)alloc(6 * 1024 * 4);
  float*    enorm    = (float*)alloc(KCODES * 4);
  ushort_t* eW0t = (ushort_t*)alloc((size_t)HID * INDIM * 2);
  ushort_t* eW1t = (ushort_t*)alloc((size_t)HID * HID * 2);
  ushort_t* eW2t = (ushort_t*)alloc((size_t)LATENT * HID * 2);
  ushort_t* embb = (ushort_t*)alloc((size_t)KCODES * LATENT * 2);
  ushort_t* dW0t = (ushort_t*)alloc((size_t)HID * LATENT * 2);
  ushort_t* dW1t = (ushort_t*)alloc((size_t)HID * HID * 2);
  ushort_t* dW2t = (ushort_t*)alloc((size_t)INDIM * HID * 2);
  ushort_t* act0 = (ushort_t*)alloc((size_t)BB * INDIM * 2);
  ushort_t* hA   = (ushort_t*)alloc((size_t)BB * HID * 2);
  ushort_t* hB   = (ushort_t*)alloc((size_t)BB * HID * 2);
  ushort_t* tA   = (ushort_t*)alloc((size_t)KCODES * HID * 2);   // decoder table L0
  ushort_t* tB   = (ushort_t*)alloc((size_t)KCODES * HID * 2);   // decoder table L1
  float*    rt   = (float*)   alloc((size_t)KCODES * INDIM * 4); // recon table (f32)
  int*      codes = (int*)    alloc((size_t)BB * 4);
  float*    loss_part = (float*)alloc((size_t)512 * 4);

  const long z_off  = (long)BB * INDIM;
  const long zq_off = z_off + (long)BB * LATENT;
  const long l_off  = zq_off + (long)BB * LATENT;

  // ---- prep ----
  k_sniff<<<1, 64, 0, stream>>>((const ushort_t*)action, flag);
  {
    const int A8 = BB * INDIM / 8, E8 = KCODES * LATENT / 8;
    int total = A8 + E8 + 6144 + KCODES;
    k_prep<<<(total + 255) / 256, 256, 0, stream>>>(action, act0, emb, embb,
        eb0, eb1, eb2, db0, db1, db2, biasf, enorm, flag);
  }
  k_tcvt6<<<2816, 256, 0, stream>>>(eW0, eW0t, eW1, eW1t, eW2, eW2t,
                                    dW0, dW0t, dW1, dW1t, dW2, dW2t, flag);

  // ---- enc-L0 (K=256, 1024 blk) + decoder table L0 (K=128, 32 blk) ----
  k_gemmw<<<1056, 256, 0, stream>>>(act0, eW0t, biasf + 0, INDIM, hA,
      1024, embb, dW0t, biasf + 3072, LATENT, tA);

  // ---- enc-L1 (K=1024, 1024 blk) + decoder table L1 (K=1024, 32 blk) ----
  k_gemmw<<<1056, 256, 0, stream>>>(hA, eW1t, biasf + 1024, HID, hB,
      1024, tA, dW1t, biasf + 4096, HID, tB);

  // ---- fused z-GEMM + VQ (512 blk) + recon table (16 blk) ----
  k_zvq<<<528, 256, 0, stream>>>(hB, eW2t, biasf + 2048, embb, enorm,
      codes, d_out, z_off, zq_off, loss_part, flag,
      tB, dW2t, biasf + 5120, rt);

  // ---- decoder = table gather ----
  k_rgather<<<BB / 8, 256, 0, stream>>>(rt, codes, d_out, flag);

  k_lossfin<<<1, 256, 0, stream>>>(loss_part, d_out, l_off, flag);
}